// Round 1
// baseline (841.273 us; speedup 1.0000x reference)
//
#include <hip/hip_runtime.h>
#include <hip/hip_bf16.h>
#include <cstdint>

#define HEADS 4
#define HID 128
#define F_OUT 512   // HEADS*HID
#define NEG_SLOPE 0.2f
#define GAT_EPS 1e-16f

// ---------------------------------------------------------------------------
// edge_index dtype detection: reference declares int64 but JAX w/o x64 makes
// int32. If data is int64 (values < 2^31), every odd 32-bit word is 0.
// Probability that 2048 random int32 src indices are all 0 is nil.
__global__ __launch_bounds__(256) void detect_i64_kernel(const unsigned int* __restrict__ e,
                                                         int* __restrict__ flag) {
  __shared__ int nz;
  if (threadIdx.x == 0) nz = 0;
  __syncthreads();
  for (int i = threadIdx.x; i < 2048; i += blockDim.x) {
    if (e[2 * i + 1] != 0u) atomicOr(&nz, 1);
  }
  __syncthreads();
  if (threadIdx.x == 0) *flag = (nz == 0) ? 1 : 0;
}

__device__ __forceinline__ int edge_at(const int* __restrict__ e32,
                                       const long long* __restrict__ e64,
                                       int f, int i) {
  return f ? (int)e64[i] : e32[i];
}

// ---------------------------------------------------------------------------
// CSR build by dst (edges 0..E-1 from edge_index, E..E+N-1 are self loops)
__global__ __launch_bounds__(256) void hist_kernel(const int* __restrict__ e32,
                                                   const long long* __restrict__ e64,
                                                   const int* __restrict__ flag,
                                                   int* __restrict__ counts, int E, int N) {
  int i = blockIdx.x * 256 + threadIdx.x;
  int total = E + N;
  if (i >= total) return;
  int f = *flag;
  int dst = (i < E) ? edge_at(e32, e64, f, E + i) : (i - E);
  atomicAdd(&counts[dst], 1);
}

__global__ __launch_bounds__(1024) void scan_kernel(const int* __restrict__ counts,
                                                    int* __restrict__ offsets,
                                                    int* __restrict__ cursor, int N) {
  __shared__ int buf[1024];
  __shared__ int carry_s;
  if (threadIdx.x == 0) carry_s = 0;
  __syncthreads();
  for (int base = 0; base < N; base += 1024) {
    int i = base + threadIdx.x;
    int v = (i < N) ? counts[i] : 0;
    buf[threadIdx.x] = v;
    __syncthreads();
    for (int off = 1; off < 1024; off <<= 1) {
      int t = (threadIdx.x >= off) ? buf[threadIdx.x - off] : 0;
      __syncthreads();
      buf[threadIdx.x] += t;
      __syncthreads();
    }
    int excl = carry_s + buf[threadIdx.x] - v;
    if (i < N) { offsets[i] = excl; cursor[i] = excl; }
    __syncthreads();
    if (threadIdx.x == 0) carry_s += buf[1023];
    __syncthreads();
  }
  if (threadIdx.x == 0) offsets[N] = carry_s;
}

__global__ __launch_bounds__(256) void scatter_kernel(const int* __restrict__ e32,
                                                      const long long* __restrict__ e64,
                                                      const int* __restrict__ flag,
                                                      int* __restrict__ cursor,
                                                      int* __restrict__ csr_src, int E, int N) {
  int i = blockIdx.x * 256 + threadIdx.x;
  int total = E + N;
  if (i >= total) return;
  int f = *flag;
  int src, dst;
  if (i < E) { src = edge_at(e32, e64, f, i); dst = edge_at(e32, e64, f, E + i); }
  else       { src = i - E; dst = src; }
  int pos = atomicAdd(&cursor[dst], 1);
  csr_src[pos] = src;
}

// ---------------------------------------------------------------------------
// fp32 tiled GEMM: C[M,512] = A[M,K] @ B[K,512]; BM=BN=64, BK=16, 4x4/thread
__global__ __launch_bounds__(256) void gemm_kernel(const float* __restrict__ A,
                                                   const float* __restrict__ B,
                                                   float* __restrict__ C, int M, int K) {
  const int BM = 64, BN = 64, BK = 16;
  __shared__ float As[BK][BM];
  __shared__ float Bs[BK][BN];
  int tid = threadIdx.x;
  int tx = tid & 15, ty = tid >> 4;
  int rowBase = blockIdx.x * BM, colBase = blockIdx.y * BN;
  float acc[4][4] = {};
  int aRow = tid >> 2;          // 0..63
  int aColq = (tid & 3) * 4;    // 0,4,8,12
  int bRow = tid >> 4;          // 0..15
  int bCol = (tid & 15) * 4;    // 0..60
  for (int k0 = 0; k0 < K; k0 += BK) {
    float4 av = make_float4(0.f, 0.f, 0.f, 0.f);
    int gr = rowBase + aRow;
    if (gr < M) av = *(const float4*)&A[(size_t)gr * K + k0 + aColq];
    As[aColq + 0][aRow] = av.x;
    As[aColq + 1][aRow] = av.y;
    As[aColq + 2][aRow] = av.z;
    As[aColq + 3][aRow] = av.w;
    *(float4*)&Bs[bRow][bCol] =
        *(const float4*)&B[(size_t)(k0 + bRow) * F_OUT + colBase + bCol];
    __syncthreads();
#pragma unroll
    for (int k = 0; k < BK; k++) {
      float a4[4], b4[4];
#pragma unroll
      for (int q = 0; q < 4; q++) { a4[q] = As[k][ty * 4 + q]; b4[q] = Bs[k][tx * 4 + q]; }
#pragma unroll
      for (int i2 = 0; i2 < 4; i2++)
#pragma unroll
        for (int j2 = 0; j2 < 4; j2++) acc[i2][j2] += a4[i2] * b4[j2];
    }
    __syncthreads();
  }
#pragma unroll
  for (int i2 = 0; i2 < 4; i2++) {
    int gr = rowBase + ty * 4 + i2;
    if (gr < M) {
      float4 v = make_float4(acc[i2][0], acc[i2][1], acc[i2][2], acc[i2][3]);
      *(float4*)&C[(size_t)gr * F_OUT + colBase + tx * 4] = v;
    }
  }
}

// ---------------------------------------------------------------------------
// a_s[n,h] = dot(h[n,h,:], att_src[h,:]); a_d likewise. One block/node, wave=head.
__global__ __launch_bounds__(256) void attdot_kernel(const float* __restrict__ h,
                                                     const float* __restrict__ att_s,
                                                     const float* __restrict__ att_d,
                                                     float* __restrict__ a_s,
                                                     float* __restrict__ a_d, int N) {
  int n = blockIdx.x;
  int w = threadIdx.x >> 6;
  int lane = threadIdx.x & 63;
  float2 hv  = *(const float2*)&h[(size_t)n * F_OUT + w * HID + lane * 2];
  float2 sv  = *(const float2*)&att_s[w * HID + lane * 2];
  float2 dv  = *(const float2*)&att_d[w * HID + lane * 2];
  float s = hv.x * sv.x + hv.y * sv.y;
  float d = hv.x * dv.x + hv.y * dv.y;
#pragma unroll
  for (int off = 32; off > 0; off >>= 1) {
    s += __shfl_down(s, off);
    d += __shfl_down(d, off);
  }
  if (lane == 0) {
    a_s[n * HEADS + w] = s;
    a_d[n * HEADS + w] = d;
  }
}

// ---------------------------------------------------------------------------
// Per-dst softmax + weighted aggregation + head-mean + bias + relu.
// One block/node; wave w = head; each lane holds 2 channels.
__global__ __launch_bounds__(256) void aggregate_kernel(const float* __restrict__ h,
                                                        const float* __restrict__ a_s,
                                                        const float* __restrict__ a_d,
                                                        const int* __restrict__ offsets,
                                                        const int* __restrict__ csr_src,
                                                        const float* __restrict__ bias,
                                                        float* __restrict__ out, int N) {
  int n = blockIdx.x;
  int w = threadIdx.x >> 6;
  int lane = threadIdx.x & 63;
  int beg = offsets[n], end = offsets[n + 1];
  float adn = a_d[n * HEADS + w];

  float m = -1e30f;
  for (int i = beg; i < end; i++) {
    int s = csr_src[i];
    float al = a_s[s * HEADS + w] + adn;
    al = (al > 0.f) ? al : al * NEG_SLOPE;
    m = fmaxf(m, al);
  }
  float denom = 0.f;
  float accx = 0.f, accy = 0.f;
  for (int i = beg; i < end; i++) {
    int s = csr_src[i];
    float al = a_s[s * HEADS + w] + adn;
    al = (al > 0.f) ? al : al * NEG_SLOPE;
    float ex = __expf(al - m);
    denom += ex;
    float2 hv = *(const float2*)&h[(size_t)s * F_OUT + w * HID + lane * 2];
    accx += hv.x * ex;
    accy += hv.y * ex;
  }
  float inv = 1.f / (denom + GAT_EPS);

  __shared__ float red[HEADS][HID];
  red[w][lane * 2 + 0] = accx * inv;
  red[w][lane * 2 + 1] = accy * inv;
  __syncthreads();
  if (threadIdx.x < HID) {
    int c = threadIdx.x;
    float v = (red[0][c] + red[1][c] + red[2][c] + red[3][c]) * 0.25f + bias[c];
    v = fmaxf(v, 0.f);  // both layers end in relu
    out[(size_t)n * HID + c] = v;
  }
}

// ---------------------------------------------------------------------------
extern "C" void kernel_launch(void* const* d_in, const int* in_sizes, int n_in,
                              void* d_out, int out_size, void* d_ws, size_t ws_size,
                              hipStream_t stream) {
  const float* x   = (const float*)d_in[0];
  const int* e32   = (const int*)d_in[1];
  const long long* e64 = (const long long*)d_in[1];
  const float* W1  = (const float*)d_in[2];
  const float* as1 = (const float*)d_in[3];
  const float* ad1 = (const float*)d_in[4];
  const float* b1  = (const float*)d_in[5];
  const float* W2  = (const float*)d_in[6];
  const float* as2 = (const float*)d_in[7];
  const float* ad2 = (const float*)d_in[8];
  const float* b2  = (const float*)d_in[9];

  int F_in = in_sizes[2] / F_OUT;       // 256
  int N = in_sizes[0] / F_in;           // 50000
  int E = in_sizes[1] / 2;              // 400000
  int Etot = E + N;

  char* ws = (char*)d_ws;
  size_t off = 0;
  auto alloc = [&](size_t bytes) -> void* {
    void* p = ws + off;
    off = (off + bytes + 255) & ~(size_t)255;
    return p;
  };
  float* h      = (float*)alloc((size_t)N * F_OUT * 4);   // 102.4 MB (reused both layers)
  float* out1   = (float*)alloc((size_t)N * HID * 4);     // 25.6 MB
  float* a_s    = (float*)alloc((size_t)N * HEADS * 4);
  float* a_d    = (float*)alloc((size_t)N * HEADS * 4);
  int* counts   = (int*)alloc((size_t)(N + 1) * 4);
  int* offsets  = (int*)alloc((size_t)(N + 1) * 4);
  int* cursor   = (int*)alloc((size_t)N * 4);
  int* csr_src  = (int*)alloc((size_t)Etot * 4);
  int* flag     = (int*)alloc(256);
  if (off > ws_size) return;  // workspace too small — bail (will fail validation loudly)

  hipMemsetAsync(counts, 0, (size_t)N * 4, stream);
  detect_i64_kernel<<<1, 256, 0, stream>>>((const unsigned int*)d_in[1], flag);
  hist_kernel<<<(Etot + 255) / 256, 256, 0, stream>>>(e32, e64, flag, counts, E, N);
  scan_kernel<<<1, 1024, 0, stream>>>(counts, offsets, cursor, N);
  scatter_kernel<<<(Etot + 255) / 256, 256, 0, stream>>>(e32, e64, flag, cursor, csr_src, E, N);

  dim3 ggrid((N + 63) / 64, F_OUT / 64);
  // ---- layer 1 ----
  gemm_kernel<<<ggrid, 256, 0, stream>>>(x, W1, h, N, F_in);
  attdot_kernel<<<N, 256, 0, stream>>>(h, as1, ad1, a_s, a_d, N);
  aggregate_kernel<<<N, 256, 0, stream>>>(h, a_s, a_d, offsets, csr_src, b1, out1, N);
  // ---- layer 2 ----
  gemm_kernel<<<ggrid, 256, 0, stream>>>(out1, W2, h, N, HID);
  attdot_kernel<<<N, 256, 0, stream>>>(h, as2, ad2, a_s, a_d, N);
  aggregate_kernel<<<N, 256, 0, stream>>>(h, a_s, a_d, offsets, csr_src, b2, (float*)d_out, N);
}

// Round 2
// 629.224 us; speedup vs baseline: 1.3370x; 1.3370x over previous
//
#include <hip/hip_runtime.h>
#include <hip/hip_bf16.h>
#include <cstdint>

#define HEADS 4
#define HID 128
#define F_OUT 512   // HEADS*HID
#define NEG_SLOPE 0.2f
#define GAT_EPS 1e-16f

typedef __attribute__((ext_vector_type(8))) short bf16x8;
typedef __attribute__((ext_vector_type(4))) float f32x4;

__device__ __forceinline__ float bf2f(unsigned short u) {
  unsigned int x = ((unsigned int)u) << 16;
  return __builtin_bit_cast(float, x);
}
__device__ __forceinline__ unsigned short f2b(float f) {
  unsigned int u = __builtin_bit_cast(unsigned int, f);
  unsigned int r = (u + 0x7fffu + ((u >> 16) & 1u)) >> 16;  // RNE
  return (unsigned short)r;
}

// ---------------------------------------------------------------------------
// edge_index dtype detection (reference says int64; JAX w/o x64 ships int32).
__global__ __launch_bounds__(256) void detect_i64_kernel(const unsigned int* __restrict__ e,
                                                         int* __restrict__ flag) {
  __shared__ int nz;
  if (threadIdx.x == 0) nz = 0;
  __syncthreads();
  for (int i = threadIdx.x; i < 2048; i += blockDim.x) {
    if (e[2 * i + 1] != 0u) atomicOr(&nz, 1);
  }
  __syncthreads();
  if (threadIdx.x == 0) *flag = (nz == 0) ? 1 : 0;
}

__device__ __forceinline__ int edge_at(const int* __restrict__ e32,
                                       const long long* __restrict__ e64,
                                       int f, int i) {
  return f ? (int)e64[i] : e32[i];
}

// ---------------------------------------------------------------------------
// CSR build by dst (edges 0..E-1 from edge_index, E..E+N-1 are self loops)
__global__ __launch_bounds__(256) void hist_kernel(const int* __restrict__ e32,
                                                   const long long* __restrict__ e64,
                                                   const int* __restrict__ flag,
                                                   int* __restrict__ counts, int E, int N) {
  int i = blockIdx.x * 256 + threadIdx.x;
  int total = E + N;
  if (i >= total) return;
  int f = *flag;
  int dst = (i < E) ? edge_at(e32, e64, f, E + i) : (i - E);
  atomicAdd(&counts[dst], 1);
}

__global__ __launch_bounds__(1024) void scan_kernel(const int* __restrict__ counts,
                                                    int* __restrict__ offsets,
                                                    int* __restrict__ cursor, int N) {
  __shared__ int buf[1024];
  __shared__ int carry_s;
  if (threadIdx.x == 0) carry_s = 0;
  __syncthreads();
  for (int base = 0; base < N; base += 1024) {
    int i = base + threadIdx.x;
    int v = (i < N) ? counts[i] : 0;
    buf[threadIdx.x] = v;
    __syncthreads();
    for (int off = 1; off < 1024; off <<= 1) {
      int t = (threadIdx.x >= off) ? buf[threadIdx.x - off] : 0;
      __syncthreads();
      buf[threadIdx.x] += t;
      __syncthreads();
    }
    int excl = carry_s + buf[threadIdx.x] - v;
    if (i < N) { offsets[i] = excl; cursor[i] = excl; }
    __syncthreads();
    if (threadIdx.x == 0) carry_s += buf[1023];
    __syncthreads();
  }
  if (threadIdx.x == 0) offsets[N] = carry_s;
}

__global__ __launch_bounds__(256) void scatter_kernel(const int* __restrict__ e32,
                                                      const long long* __restrict__ e64,
                                                      const int* __restrict__ flag,
                                                      int* __restrict__ cursor,
                                                      int* __restrict__ csr_src, int E, int N) {
  int i = blockIdx.x * 256 + threadIdx.x;
  int total = E + N;
  if (i >= total) return;
  int f = *flag;
  int src, dst;
  if (i < E) { src = edge_at(e32, e64, f, i); dst = edge_at(e32, e64, f, E + i); }
  else       { src = i - E; dst = src; }
  int pos = atomicAdd(&cursor[dst], 1);
  csr_src[pos] = src;
}

// ---------------------------------------------------------------------------
// fp32 -> bf16 elementwise (n divisible by 4)
__global__ __launch_bounds__(256) void cvt_x_kernel(const float* __restrict__ in,
                                                    unsigned short* __restrict__ out, long n4) {
  long i = (long)blockIdx.x * 256 + threadIdx.x;
  if (i >= n4) return;
  float4 v = *(const float4*)&in[i * 4];
  ushort4 o;
  o.x = f2b(v.x); o.y = f2b(v.y); o.z = f2b(v.z); o.w = f2b(v.w);
  *(ushort4*)&out[i * 4] = o;
}

// W[K][512] fp32 -> Wt[512][K] bf16 (tiny)
__global__ __launch_bounds__(256) void cvt_w_kernel(const float* __restrict__ W,
                                                    unsigned short* __restrict__ Wt, int K) {
  int idx = blockIdx.x * 256 + threadIdx.x;
  if (idx >= K * F_OUT) return;
  int k = idx / F_OUT, c = idx % F_OUT;
  Wt[c * K + k] = f2b(W[idx]);
}

// ---------------------------------------------------------------------------
// bf16 MFMA GEMM: C[M,512](bf16) = A[M,K](bf16) @ Bt[512,K](bf16)^T
// 128x128 tile, 4 waves (2x2), 4x4 16x16x32 fragments per wave, BK=32.
#define LDK 40  // padded LDS K-stride (bf16 elems): 80B rows dodge bank conflicts
__global__ __launch_bounds__(256) void gemm_bf16_kernel(const unsigned short* __restrict__ A,
                                                        const unsigned short* __restrict__ Bt,
                                                        unsigned short* __restrict__ C,
                                                        int M, int K) {
  __shared__ unsigned short As[128][LDK];
  __shared__ unsigned short Bs[128][LDK];
  int tid = threadIdx.x;
  int lane = tid & 63, wid = tid >> 6;
  int wr = wid >> 1, wc = wid & 1;
  int rowBase = blockIdx.x * 128, colBase = blockIdx.y * 128;
  f32x4 acc[4][4];
#pragma unroll
  for (int i = 0; i < 4; i++)
#pragma unroll
    for (int j = 0; j < 4; j++) acc[i][j] = (f32x4){0.f, 0.f, 0.f, 0.f};

  int fr = lane & 15, fk = (lane >> 4) * 8;

  for (int k0 = 0; k0 < K; k0 += 32) {
#pragma unroll
    for (int i = 0; i < 2; i++) {
      int idx = i * 256 + tid;
      int r = idx >> 2, cq = (idx & 3) * 8;
      int gr = rowBase + r;
      float4 va = make_float4(0.f, 0.f, 0.f, 0.f);
      if (gr < M) va = *(const float4*)&A[(size_t)gr * K + k0 + cq];
      *(float4*)&As[r][cq] = va;
      *(float4*)&Bs[r][cq] = *(const float4*)&Bt[(size_t)(colBase + r) * K + k0 + cq];
    }
    __syncthreads();
    bf16x8 af[4], bfv[4];
#pragma unroll
    for (int mi = 0; mi < 4; mi++)
      af[mi] = *(const bf16x8*)&As[wr * 64 + mi * 16 + fr][fk];
#pragma unroll
    for (int ni = 0; ni < 4; ni++)
      bfv[ni] = *(const bf16x8*)&Bs[wc * 64 + ni * 16 + fr][fk];
#pragma unroll
    for (int mi = 0; mi < 4; mi++)
#pragma unroll
      for (int ni = 0; ni < 4; ni++)
        acc[mi][ni] = __builtin_amdgcn_mfma_f32_16x16x32_bf16(af[mi], bfv[ni], acc[mi][ni], 0, 0, 0);
    __syncthreads();
  }
  // epilogue: C/D layout col=lane&15, row=(lane>>4)*4+q
  int r0 = rowBase + wr * 64, c0 = colBase + wc * 64;
#pragma unroll
  for (int mi = 0; mi < 4; mi++) {
#pragma unroll
    for (int ni = 0; ni < 4; ni++) {
      int col = c0 + ni * 16 + (lane & 15);
#pragma unroll
      for (int q = 0; q < 4; q++) {
        int row = r0 + mi * 16 + (lane >> 4) * 4 + q;
        if (row < M) C[(size_t)row * F_OUT + col] = f2b(acc[mi][ni][q]);
      }
    }
  }
}

// ---------------------------------------------------------------------------
// a_s[n,h] = dot(h[n,h,:], att_src[h,:]); h is bf16. One block/node, wave=head.
__global__ __launch_bounds__(256) void attdot_kernel(const unsigned short* __restrict__ h,
                                                     const float* __restrict__ att_s,
                                                     const float* __restrict__ att_d,
                                                     float* __restrict__ a_s,
                                                     float* __restrict__ a_d, int N) {
  int n = blockIdx.x;
  int w = threadIdx.x >> 6;
  int lane = threadIdx.x & 63;
  ushort2 hv = *(const ushort2*)&h[(size_t)n * F_OUT + w * HID + lane * 2];
  float hx = bf2f(hv.x), hy = bf2f(hv.y);
  float2 sv = *(const float2*)&att_s[w * HID + lane * 2];
  float2 dv = *(const float2*)&att_d[w * HID + lane * 2];
  float s = hx * sv.x + hy * sv.y;
  float d = hx * dv.x + hy * dv.y;
#pragma unroll
  for (int off = 32; off > 0; off >>= 1) {
    s += __shfl_down(s, off);
    d += __shfl_down(d, off);
  }
  if (lane == 0) {
    a_s[n * HEADS + w] = s;
    a_d[n * HEADS + w] = d;
  }
}

// ---------------------------------------------------------------------------
// Per-dst softmax + weighted aggregation + head-mean + bias + relu.
// One block/node; wave w = head; each lane holds 2 channels. h is bf16.
// OUT_BF=1 -> write bf16 (layer-1 intermediate), else fp32 (final output).
template <int OUT_BF>
__global__ __launch_bounds__(256) void aggregate_kernel(const unsigned short* __restrict__ h,
                                                        const float* __restrict__ a_s,
                                                        const float* __restrict__ a_d,
                                                        const int* __restrict__ offsets,
                                                        const int* __restrict__ csr_src,
                                                        const float* __restrict__ bias,
                                                        void* __restrict__ out, int N) {
  int n = blockIdx.x;
  int w = threadIdx.x >> 6;
  int lane = threadIdx.x & 63;
  int beg = offsets[n], end = offsets[n + 1];
  float adn = a_d[n * HEADS + w];

  float m = -1e30f;
  for (int i = beg; i < end; i++) {
    int s = csr_src[i];
    float al = a_s[s * HEADS + w] + adn;
    al = (al > 0.f) ? al : al * NEG_SLOPE;
    m = fmaxf(m, al);
  }
  float denom = 0.f;
  float accx = 0.f, accy = 0.f;
  for (int i = beg; i < end; i++) {
    int s = csr_src[i];
    float al = a_s[s * HEADS + w] + adn;
    al = (al > 0.f) ? al : al * NEG_SLOPE;
    float ex = __expf(al - m);
    denom += ex;
    ushort2 hv = *(const ushort2*)&h[(size_t)s * F_OUT + w * HID + lane * 2];
    accx += bf2f(hv.x) * ex;
    accy += bf2f(hv.y) * ex;
  }
  float inv = 1.f / (denom + GAT_EPS);

  __shared__ float red[HEADS][HID];
  red[w][lane * 2 + 0] = accx * inv;
  red[w][lane * 2 + 1] = accy * inv;
  __syncthreads();
  if (threadIdx.x < HID) {
    int c = threadIdx.x;
    float v = (red[0][c] + red[1][c] + red[2][c] + red[3][c]) * 0.25f + bias[c];
    v = fmaxf(v, 0.f);  // both layers end in relu
    if (OUT_BF)
      ((unsigned short*)out)[(size_t)n * HID + c] = f2b(v);
    else
      ((float*)out)[(size_t)n * HID + c] = v;
  }
}

// ---------------------------------------------------------------------------
extern "C" void kernel_launch(void* const* d_in, const int* in_sizes, int n_in,
                              void* d_out, int out_size, void* d_ws, size_t ws_size,
                              hipStream_t stream) {
  const float* x   = (const float*)d_in[0];
  const int* e32   = (const int*)d_in[1];
  const long long* e64 = (const long long*)d_in[1];
  const float* W1  = (const float*)d_in[2];
  const float* as1 = (const float*)d_in[3];
  const float* ad1 = (const float*)d_in[4];
  const float* b1  = (const float*)d_in[5];
  const float* W2  = (const float*)d_in[6];
  const float* as2 = (const float*)d_in[7];
  const float* ad2 = (const float*)d_in[8];
  const float* b2  = (const float*)d_in[9];

  int F_in = in_sizes[2] / F_OUT;       // 256
  int N = in_sizes[0] / F_in;           // 50000
  int E = in_sizes[1] / 2;              // 400000
  int Etot = E + N;

  char* ws = (char*)d_ws;
  size_t off = 0;
  auto alloc = [&](size_t bytes) -> void* {
    void* p = ws + off;
    off = (off + bytes + 255) & ~(size_t)255;
    return p;
  };
  unsigned short* h_bf   = (unsigned short*)alloc((size_t)N * F_OUT * 2);  // 51.2 MB
  unsigned short* x_bf   = (unsigned short*)alloc((size_t)N * F_in * 2);   // 25.6 MB
  unsigned short* out1_bf= (unsigned short*)alloc((size_t)N * HID * 2);    // 12.8 MB
  unsigned short* Wt1    = (unsigned short*)alloc((size_t)F_in * F_OUT * 2);
  unsigned short* Wt2    = (unsigned short*)alloc((size_t)HID * F_OUT * 2);
  float* a_s    = (float*)alloc((size_t)N * HEADS * 4);
  float* a_d    = (float*)alloc((size_t)N * HEADS * 4);
  int* counts   = (int*)alloc((size_t)(N + 1) * 4);
  int* offsets  = (int*)alloc((size_t)(N + 1) * 4);
  int* cursor   = (int*)alloc((size_t)N * 4);
  int* csr_src  = (int*)alloc((size_t)Etot * 4);
  int* flag     = (int*)alloc(256);
  if (off > ws_size) return;

  hipMemsetAsync(counts, 0, (size_t)N * 4, stream);
  detect_i64_kernel<<<1, 256, 0, stream>>>((const unsigned int*)d_in[1], flag);
  hist_kernel<<<(Etot + 255) / 256, 256, 0, stream>>>(e32, e64, flag, counts, E, N);
  scan_kernel<<<1, 1024, 0, stream>>>(counts, offsets, cursor, N);
  scatter_kernel<<<(Etot + 255) / 256, 256, 0, stream>>>(e32, e64, flag, cursor, csr_src, E, N);

  // input conversions
  long n4x = (long)N * F_in / 4;
  cvt_x_kernel<<<(int)((n4x + 255) / 256), 256, 0, stream>>>(x, x_bf, n4x);
  cvt_w_kernel<<<(F_in * F_OUT + 255) / 256, 256, 0, stream>>>(W1, Wt1, F_in);
  cvt_w_kernel<<<(HID * F_OUT + 255) / 256, 256, 0, stream>>>(W2, Wt2, HID);

  dim3 ggrid((N + 127) / 128, F_OUT / 128);
  // ---- layer 1 ----
  gemm_bf16_kernel<<<ggrid, 256, 0, stream>>>(x_bf, Wt1, h_bf, N, F_in);
  attdot_kernel<<<N, 256, 0, stream>>>(h_bf, as1, ad1, a_s, a_d, N);
  aggregate_kernel<1><<<N, 256, 0, stream>>>(h_bf, a_s, a_d, offsets, csr_src, b1, out1_bf, N);
  // ---- layer 2 ----
  gemm_bf16_kernel<<<ggrid, 256, 0, stream>>>(out1_bf, Wt2, h_bf, N, HID);
  attdot_kernel<<<N, 256, 0, stream>>>(h_bf, as2, ad2, a_s, a_d, N);
  aggregate_kernel<0><<<N, 256, 0, stream>>>(h_bf, a_s, a_d, offsets, csr_src, b2, d_out, N);
}

// Round 3
// 461.959 us; speedup vs baseline: 1.8211x; 1.3621x over previous
//
#include <hip/hip_runtime.h>
#include <hip/hip_bf16.h>
#include <cstdint>

#define HEADS 4
#define HID 128
#define F_OUT 512   // HEADS*HID
#define NEG_SLOPE 0.2f
#define GAT_EPS 1e-16f

typedef __attribute__((ext_vector_type(8))) short bf16x8;
typedef __attribute__((ext_vector_type(4))) float f32x4;

__device__ __forceinline__ float bf2f(unsigned short u) {
  unsigned int x = ((unsigned int)u) << 16;
  return __builtin_bit_cast(float, x);
}
__device__ __forceinline__ unsigned short f2b(float f) {
  unsigned int u = __builtin_bit_cast(unsigned int, f);
  unsigned int r = (u + 0x7fffu + ((u >> 16) & 1u)) >> 16;  // RNE
  return (unsigned short)r;
}

// ---------------------------------------------------------------------------
// edge_index dtype detection (reference says int64; JAX w/o x64 ships int32).
__global__ __launch_bounds__(256) void detect_i64_kernel(const unsigned int* __restrict__ e,
                                                         int* __restrict__ flag) {
  __shared__ int nz;
  if (threadIdx.x == 0) nz = 0;
  __syncthreads();
  for (int i = threadIdx.x; i < 2048; i += blockDim.x) {
    if (e[2 * i + 1] != 0u) atomicOr(&nz, 1);
  }
  __syncthreads();
  if (threadIdx.x == 0) *flag = (nz == 0) ? 1 : 0;
}

__device__ __forceinline__ int edge_at(const int* __restrict__ e32,
                                       const long long* __restrict__ e64,
                                       int f, int i) {
  return f ? (int)e64[i] : e32[i];
}

// ---------------------------------------------------------------------------
// CSR build by dst (edges 0..E-1 from edge_index, E..E+N-1 are self loops)
__global__ __launch_bounds__(256) void hist_kernel(const int* __restrict__ e32,
                                                   const long long* __restrict__ e64,
                                                   const int* __restrict__ flag,
                                                   int* __restrict__ counts, int E, int N) {
  int i = blockIdx.x * 256 + threadIdx.x;
  int total = E + N;
  if (i >= total) return;
  int f = *flag;
  int dst = (i < E) ? edge_at(e32, e64, f, E + i) : (i - E);
  atomicAdd(&counts[dst], 1);
}

__global__ __launch_bounds__(1024) void scan_kernel(const int* __restrict__ counts,
                                                    int* __restrict__ offsets,
                                                    int* __restrict__ cursor, int N) {
  __shared__ int buf[1024];
  __shared__ int carry_s;
  if (threadIdx.x == 0) carry_s = 0;
  __syncthreads();
  for (int base = 0; base < N; base += 1024) {
    int i = base + threadIdx.x;
    int v = (i < N) ? counts[i] : 0;
    buf[threadIdx.x] = v;
    __syncthreads();
    for (int off = 1; off < 1024; off <<= 1) {
      int t = (threadIdx.x >= off) ? buf[threadIdx.x - off] : 0;
      __syncthreads();
      buf[threadIdx.x] += t;
      __syncthreads();
    }
    int excl = carry_s + buf[threadIdx.x] - v;
    if (i < N) { offsets[i] = excl; cursor[i] = excl; }
    __syncthreads();
    if (threadIdx.x == 0) carry_s += buf[1023];
    __syncthreads();
  }
  if (threadIdx.x == 0) offsets[N] = carry_s;
}

__global__ __launch_bounds__(256) void scatter_kernel(const int* __restrict__ e32,
                                                      const long long* __restrict__ e64,
                                                      const int* __restrict__ flag,
                                                      int* __restrict__ cursor,
                                                      int* __restrict__ csr_src,
                                                      int* __restrict__ csr_dst, int E, int N) {
  int i = blockIdx.x * 256 + threadIdx.x;
  int total = E + N;
  if (i >= total) return;
  int f = *flag;
  int src, dst;
  if (i < E) { src = edge_at(e32, e64, f, i); dst = edge_at(e32, e64, f, E + i); }
  else       { src = i - E; dst = src; }
  int pos = atomicAdd(&cursor[dst], 1);
  csr_src[pos] = src;
  csr_dst[pos] = dst;
}

// ---------------------------------------------------------------------------
// fp32 -> bf16 elementwise (n divisible by 4)
__global__ __launch_bounds__(256) void cvt_x_kernel(const float* __restrict__ in,
                                                    unsigned short* __restrict__ out, long n4) {
  long i = (long)blockIdx.x * 256 + threadIdx.x;
  if (i >= n4) return;
  float4 v = *(const float4*)&in[i * 4];
  ushort4 o;
  o.x = f2b(v.x); o.y = f2b(v.y); o.z = f2b(v.z); o.w = f2b(v.w);
  *(ushort4*)&out[i * 4] = o;
}

// W[K][512] fp32 -> Wt[512][K] bf16 (tiny)
__global__ __launch_bounds__(256) void cvt_w_kernel(const float* __restrict__ W,
                                                    unsigned short* __restrict__ Wt, int K) {
  int idx = blockIdx.x * 256 + threadIdx.x;
  if (idx >= K * F_OUT) return;
  int k = idx / F_OUT, c = idx % F_OUT;
  Wt[c * K + k] = f2b(W[idx]);
}

// ---------------------------------------------------------------------------
// bf16 MFMA GEMM: C[M,512](bf16) = A[M,K](bf16) @ Bt[512,K](bf16)^T
// 128x128 tile, 4 waves (2x2), 4x4 16x16x32 fragments per wave, BK=32.
#define LDK 40  // padded LDS K-stride (bf16 elems)
__global__ __launch_bounds__(256) void gemm_bf16_kernel(const unsigned short* __restrict__ A,
                                                        const unsigned short* __restrict__ Bt,
                                                        unsigned short* __restrict__ C,
                                                        int M, int K) {
  __shared__ unsigned short As[128][LDK];
  __shared__ unsigned short Bs[128][LDK];
  int tid = threadIdx.x;
  int lane = tid & 63, wid = tid >> 6;
  int wr = wid >> 1, wc = wid & 1;
  int rowBase = blockIdx.x * 128, colBase = blockIdx.y * 128;
  f32x4 acc[4][4];
#pragma unroll
  for (int i = 0; i < 4; i++)
#pragma unroll
    for (int j = 0; j < 4; j++) acc[i][j] = (f32x4){0.f, 0.f, 0.f, 0.f};

  int fr = lane & 15, fk = (lane >> 4) * 8;

  for (int k0 = 0; k0 < K; k0 += 32) {
#pragma unroll
    for (int i = 0; i < 2; i++) {
      int idx = i * 256 + tid;
      int r = idx >> 2, cq = (idx & 3) * 8;
      int gr = rowBase + r;
      float4 va = make_float4(0.f, 0.f, 0.f, 0.f);
      if (gr < M) va = *(const float4*)&A[(size_t)gr * K + k0 + cq];
      *(float4*)&As[r][cq] = va;
      *(float4*)&Bs[r][cq] = *(const float4*)&Bt[(size_t)(colBase + r) * K + k0 + cq];
    }
    __syncthreads();
    bf16x8 af[4], bfv[4];
#pragma unroll
    for (int mi = 0; mi < 4; mi++)
      af[mi] = *(const bf16x8*)&As[wr * 64 + mi * 16 + fr][fk];
#pragma unroll
    for (int ni = 0; ni < 4; ni++)
      bfv[ni] = *(const bf16x8*)&Bs[wc * 64 + ni * 16 + fr][fk];
#pragma unroll
    for (int mi = 0; mi < 4; mi++)
#pragma unroll
      for (int ni = 0; ni < 4; ni++)
        acc[mi][ni] = __builtin_amdgcn_mfma_f32_16x16x32_bf16(af[mi], bfv[ni], acc[mi][ni], 0, 0, 0);
    __syncthreads();
  }
  int r0 = rowBase + wr * 64, c0 = colBase + wc * 64;
#pragma unroll
  for (int mi = 0; mi < 4; mi++) {
#pragma unroll
    for (int ni = 0; ni < 4; ni++) {
      int col = c0 + ni * 16 + (lane & 15);
#pragma unroll
      for (int q = 0; q < 4; q++) {
        int row = r0 + mi * 16 + (lane >> 4) * 4 + q;
        if (row < M) C[(size_t)row * F_OUT + col] = f2b(acc[mi][ni][q]);
      }
    }
  }
}

// ---------------------------------------------------------------------------
// attdot: wave = node (grid-stride); 16-lane group = head; ushort8 row loads.
__global__ __launch_bounds__(256) void attdot_kernel(const unsigned short* __restrict__ h,
                                                     const float* __restrict__ att_s,
                                                     const float* __restrict__ att_d,
                                                     float* __restrict__ a_s,
                                                     float* __restrict__ a_d, int N) {
  int lane = threadIdx.x & 63;
  int hh = lane >> 4, sl = lane & 15;
  int gwave = (blockIdx.x * 256 + threadIdx.x) >> 6;
  int nwaves = (gridDim.x * 256) >> 6;
  float asv[8], adv[8];
#pragma unroll
  for (int j = 0; j < 8; j++) {
    asv[j] = att_s[hh * HID + sl * 8 + j];
    adv[j] = att_d[hh * HID + sl * 8 + j];
  }
  for (int n = gwave; n < N; n += nwaves) {
    bf16x8 hv = *(const bf16x8*)&h[(size_t)n * F_OUT + hh * HID + sl * 8];
    float s = 0.f, d = 0.f;
#pragma unroll
    for (int j = 0; j < 8; j++) {
      float f = bf2f((unsigned short)hv[j]);
      s += f * asv[j];
      d += f * adv[j];
    }
#pragma unroll
    for (int off = 1; off < 16; off <<= 1) {
      s += __shfl_xor(s, off);
      d += __shfl_xor(d, off);
    }
    if (sl == 0) {
      a_s[n * HEADS + hh] = s;
      a_d[n * HEADS + hh] = d;
    }
  }
}

// ---------------------------------------------------------------------------
// edge-parallel raw attention: alpha[i*4+h] = leaky(a_s[src]+a_d[dst])
__global__ __launch_bounds__(256) void alpha_kernel(const int* __restrict__ csr_src,
                                                    const int* __restrict__ csr_dst,
                                                    const float* __restrict__ a_s,
                                                    const float* __restrict__ a_d,
                                                    float* __restrict__ alpha, int Etot) {
  int t = blockIdx.x * 256 + threadIdx.x;
  if (t >= Etot * HEADS) return;
  int i = t >> 2, hh = t & 3;
  int s = csr_src[i], d = csr_dst[i];
  float al = a_s[s * HEADS + hh] + a_d[d * HEADS + hh];
  al = (al > 0.f) ? al : al * NEG_SLOPE;
  alpha[t] = al;
}

// ---------------------------------------------------------------------------
// per-(node,head): segment softmax over alpha -> normalized weights in place
__global__ __launch_bounds__(256) void norm_kernel(const int* __restrict__ offsets,
                                                   float* __restrict__ alpha, int N) {
  int t = blockIdx.x * 256 + threadIdx.x;
  if (t >= N * HEADS) return;
  int n = t >> 2, hh = t & 3;
  int beg = offsets[n], end = offsets[n + 1];
  float m = -1e30f;
  for (int i = beg; i < end; i++) m = fmaxf(m, alpha[i * HEADS + hh]);
  float denom = 0.f;
  for (int i = beg; i < end; i++) {
    float ex = __expf(alpha[i * HEADS + hh] - m);
    alpha[i * HEADS + hh] = ex;
    denom += ex;
  }
  float inv = 1.f / (denom + GAT_EPS);
  for (int i = beg; i < end; i++) alpha[i * HEADS + hh] *= inv;
}

// ---------------------------------------------------------------------------
// aggregate: block = node, wave = head, 4 edge-slots x 16 lanes; ushort8 rows.
// OUT_BF=1 -> bf16 out (layer-1 intermediate), else fp32 (final).
template <int OUT_BF>
__global__ __launch_bounds__(256) void aggregate_kernel(const unsigned short* __restrict__ h,
                                                        const float* __restrict__ wexp,
                                                        const int* __restrict__ offsets,
                                                        const int* __restrict__ csr_src,
                                                        const float* __restrict__ bias,
                                                        void* __restrict__ out, int N) {
  int n = blockIdx.x;
  int w = threadIdx.x >> 6;      // head
  int lane = threadIdx.x & 63;
  int slot = lane >> 4, sl = lane & 15;
  int beg = offsets[n], end = offsets[n + 1];

  float acc[8];
#pragma unroll
  for (int j = 0; j < 8; j++) acc[j] = 0.f;

  int e = beg + slot;
  int s = 0; float wgt = 0.f;
  if (e < end) { s = csr_src[e]; wgt = wexp[e * HEADS + w]; }
  while (e < end) {
    int ne = e + 4;
    int ns = 0; float nw = 0.f;
    if (ne < end) { ns = csr_src[ne]; nw = wexp[ne * HEADS + w]; }
    bf16x8 hv = *(const bf16x8*)&h[(size_t)s * F_OUT + w * HID + sl * 8];
#pragma unroll
    for (int j = 0; j < 8; j++) acc[j] += bf2f((unsigned short)hv[j]) * wgt;
    e = ne; s = ns; wgt = nw;
  }
#pragma unroll
  for (int j = 0; j < 8; j++) {
    acc[j] += __shfl_xor(acc[j], 16);
    acc[j] += __shfl_xor(acc[j], 32);
  }

  __shared__ float red[HEADS][HID];
  if (slot == 0) {
#pragma unroll
    for (int j = 0; j < 8; j++) red[w][sl * 8 + j] = acc[j];
  }
  __syncthreads();
  if (threadIdx.x < HID) {
    int c = threadIdx.x;
    float v = (red[0][c] + red[1][c] + red[2][c] + red[3][c]) * 0.25f + bias[c];
    v = fmaxf(v, 0.f);  // both layers end in relu
    if (OUT_BF)
      ((unsigned short*)out)[(size_t)n * HID + c] = f2b(v);
    else
      ((float*)out)[(size_t)n * HID + c] = v;
  }
}

// ---------------------------------------------------------------------------
extern "C" void kernel_launch(void* const* d_in, const int* in_sizes, int n_in,
                              void* d_out, int out_size, void* d_ws, size_t ws_size,
                              hipStream_t stream) {
  const float* x   = (const float*)d_in[0];
  const int* e32   = (const int*)d_in[1];
  const long long* e64 = (const long long*)d_in[1];
  const float* W1  = (const float*)d_in[2];
  const float* as1 = (const float*)d_in[3];
  const float* ad1 = (const float*)d_in[4];
  const float* b1  = (const float*)d_in[5];
  const float* W2  = (const float*)d_in[6];
  const float* as2 = (const float*)d_in[7];
  const float* ad2 = (const float*)d_in[8];
  const float* b2  = (const float*)d_in[9];

  int F_in = in_sizes[2] / F_OUT;       // 256
  int N = in_sizes[0] / F_in;           // 50000
  int E = in_sizes[1] / 2;              // 400000
  int Etot = E + N;

  char* ws = (char*)d_ws;
  size_t off = 0;
  auto alloc = [&](size_t bytes) -> void* {
    void* p = ws + off;
    off = (off + bytes + 255) & ~(size_t)255;
    return p;
  };
  unsigned short* h_bf   = (unsigned short*)alloc((size_t)N * F_OUT * 2);  // 51.2 MB
  unsigned short* x_bf   = (unsigned short*)alloc((size_t)N * F_in * 2);   // 25.6 MB
  unsigned short* out1_bf= (unsigned short*)alloc((size_t)N * HID * 2);    // 12.8 MB
  unsigned short* Wt1    = (unsigned short*)alloc((size_t)F_in * F_OUT * 2);
  unsigned short* Wt2    = (unsigned short*)alloc((size_t)HID * F_OUT * 2);
  float* a_s    = (float*)alloc((size_t)N * HEADS * 4);
  float* a_d    = (float*)alloc((size_t)N * HEADS * 4);
  float* alpha  = (float*)alloc((size_t)Etot * HEADS * 4);                 // 7.2 MB
  int* counts   = (int*)alloc((size_t)(N + 1) * 4);
  int* offsets  = (int*)alloc((size_t)(N + 1) * 4);
  int* cursor   = (int*)alloc((size_t)N * 4);
  int* csr_src  = (int*)alloc((size_t)Etot * 4);
  int* csr_dst  = (int*)alloc((size_t)Etot * 4);
  int* flag     = (int*)alloc(256);
  if (off > ws_size) return;

  hipMemsetAsync(counts, 0, (size_t)N * 4, stream);
  detect_i64_kernel<<<1, 256, 0, stream>>>((const unsigned int*)d_in[1], flag);
  hist_kernel<<<(Etot + 255) / 256, 256, 0, stream>>>(e32, e64, flag, counts, E, N);
  scan_kernel<<<1, 1024, 0, stream>>>(counts, offsets, cursor, N);
  scatter_kernel<<<(Etot + 255) / 256, 256, 0, stream>>>(e32, e64, flag, cursor, csr_src, csr_dst, E, N);

  long n4x = (long)N * F_in / 4;
  cvt_x_kernel<<<(int)((n4x + 255) / 256), 256, 0, stream>>>(x, x_bf, n4x);
  cvt_w_kernel<<<(F_in * F_OUT + 255) / 256, 256, 0, stream>>>(W1, Wt1, F_in);
  cvt_w_kernel<<<(HID * F_OUT + 255) / 256, 256, 0, stream>>>(W2, Wt2, HID);

  dim3 ggrid((N + 127) / 128, F_OUT / 128);
  int ablocks = (Etot * HEADS + 255) / 256;
  int nblocks = (N * HEADS + 255) / 256;
  // ---- layer 1 ----
  gemm_bf16_kernel<<<ggrid, 256, 0, stream>>>(x_bf, Wt1, h_bf, N, F_in);
  attdot_kernel<<<512, 256, 0, stream>>>(h_bf, as1, ad1, a_s, a_d, N);
  alpha_kernel<<<ablocks, 256, 0, stream>>>(csr_src, csr_dst, a_s, a_d, alpha, Etot);
  norm_kernel<<<nblocks, 256, 0, stream>>>(offsets, alpha, N);
  aggregate_kernel<1><<<N, 256, 0, stream>>>(h_bf, alpha, offsets, csr_src, b1, out1_bf, N);
  // ---- layer 2 ----
  gemm_bf16_kernel<<<ggrid, 256, 0, stream>>>(out1_bf, Wt2, h_bf, N, HID);
  attdot_kernel<<<512, 256, 0, stream>>>(h_bf, as2, ad2, a_s, a_d, N);
  alpha_kernel<<<ablocks, 256, 0, stream>>>(csr_src, csr_dst, a_s, a_d, alpha, Etot);
  norm_kernel<<<nblocks, 256, 0, stream>>>(offsets, alpha, N);
  aggregate_kernel<0><<<N, 256, 0, stream>>>(h_bf, alpha, offsets, csr_src, b2, d_out, N);
}

// Round 4
// 379.041 us; speedup vs baseline: 2.2195x; 1.2188x over previous
//
#include <hip/hip_runtime.h>
#include <hip/hip_bf16.h>
#include <cstdint>

#define HEADS 4
#define HID 128
#define F_OUT 512   // HEADS*HID
#define NEG_SLOPE 0.2f
#define GAT_EPS 1e-16f

typedef __attribute__((ext_vector_type(8))) short bf16x8;
typedef __attribute__((ext_vector_type(4))) float f32x4;

__device__ __forceinline__ float bf2f(unsigned short u) {
  unsigned int x = ((unsigned int)u) << 16;
  return __builtin_bit_cast(float, x);
}
__device__ __forceinline__ unsigned short f2b(float f) {
  unsigned int u = __builtin_bit_cast(unsigned int, f);
  unsigned int r = (u + 0x7fffu + ((u >> 16) & 1u)) >> 16;  // RNE
  return (unsigned short)r;
}

// ---------------------------------------------------------------------------
// edge_index dtype detection (reference says int64; JAX w/o x64 ships int32).
__global__ __launch_bounds__(256) void detect_i64_kernel(const unsigned int* __restrict__ e,
                                                         int* __restrict__ flag) {
  __shared__ int nz;
  if (threadIdx.x == 0) nz = 0;
  __syncthreads();
  for (int i = threadIdx.x; i < 2048; i += blockDim.x) {
    if (e[2 * i + 1] != 0u) atomicOr(&nz, 1);
  }
  __syncthreads();
  if (threadIdx.x == 0) *flag = (nz == 0) ? 1 : 0;
}

__device__ __forceinline__ int edge_at(const int* __restrict__ e32,
                                       const long long* __restrict__ e64,
                                       int f, int i) {
  return f ? (int)e64[i] : e32[i];
}

// ---------------------------------------------------------------------------
// CSR build by dst (edges 0..E-1 from edge_index, E..E+N-1 are self loops)
__global__ __launch_bounds__(256) void hist_kernel(const int* __restrict__ e32,
                                                   const long long* __restrict__ e64,
                                                   const int* __restrict__ flag,
                                                   int* __restrict__ counts, int E, int N) {
  int i = blockIdx.x * 256 + threadIdx.x;
  int total = E + N;
  if (i >= total) return;
  int f = *flag;
  int dst = (i < E) ? edge_at(e32, e64, f, E + i) : (i - E);
  atomicAdd(&counts[dst], 1);
}

// ---- multi-block exclusive scan over counts[0..N) -> offsets, cursor -------
// A: per-1024-chunk sums
__global__ __launch_bounds__(256) void scan_partial_kernel(const int* __restrict__ counts,
                                                           int* __restrict__ partials, int N) {
  int t = threadIdx.x;
  int lane = t & 63, wv = t >> 6;
  int idx = blockIdx.x * 1024 + t * 4;
  int4 v = make_int4(0, 0, 0, 0);
  if (idx + 3 < N) v = *(const int4*)&counts[idx];
  else {
    if (idx + 0 < N) v.x = counts[idx + 0];
    if (idx + 1 < N) v.y = counts[idx + 1];
    if (idx + 2 < N) v.z = counts[idx + 2];
  }
  int s = v.x + v.y + v.z + v.w;
#pragma unroll
  for (int off = 32; off > 0; off >>= 1) s += __shfl_xor(s, off);
  __shared__ int wsum[4];
  if (lane == 0) wsum[wv] = s;
  __syncthreads();
  if (t == 0) partials[blockIdx.x] = wsum[0] + wsum[1] + wsum[2] + wsum[3];
}

// B: exclusive-scan the (<=1024) partials in place; write grand total to offsets[N]
__global__ __launch_bounds__(256) void scan_base_kernel(int* __restrict__ partials,
                                                        int* __restrict__ offsets,
                                                        int nblocks, int N) {
  __shared__ int buf[1024];
  int t = threadIdx.x;
  for (int i = t; i < nblocks; i += 256) buf[i] = partials[i];
  __syncthreads();
  if (t == 0) {
    int run = 0;
    for (int i = 0; i < nblocks; i++) { int c = buf[i]; buf[i] = run; run += c; }
    offsets[N] = run;
  }
  __syncthreads();
  for (int i = t; i < nblocks; i += 256) partials[i] = buf[i];
}

// C: rescan each chunk with the block base; write offsets + cursor
__global__ __launch_bounds__(256) void scan_final_kernel(const int* __restrict__ counts,
                                                         const int* __restrict__ partials,
                                                         int* __restrict__ offsets,
                                                         int* __restrict__ cursor, int N) {
  int t = threadIdx.x;
  int lane = t & 63, wv = t >> 6;
  int idx = blockIdx.x * 1024 + t * 4;
  int4 v = make_int4(0, 0, 0, 0);
  if (idx + 3 < N) v = *(const int4*)&counts[idx];
  else {
    if (idx + 0 < N) v.x = counts[idx + 0];
    if (idx + 1 < N) v.y = counts[idx + 1];
    if (idx + 2 < N) v.z = counts[idx + 2];
  }
  int s1 = v.x, s2 = s1 + v.y, s3 = s2 + v.z, s4 = s3 + v.w;
  int val = s4;
#pragma unroll
  for (int off = 1; off < 64; off <<= 1) {
    int y = __shfl_up(val, off);
    if (lane >= off) val += y;
  }
  __shared__ int wsum[4];
  if (lane == 63) wsum[wv] = val;
  __syncthreads();
  int wbase = 0;
  for (int i = 0; i < wv; i++) wbase += wsum[i];
  int excl = partials[blockIdx.x] + wbase + (val - s4);
  if (idx + 0 < N) { offsets[idx + 0] = excl;      cursor[idx + 0] = excl; }
  if (idx + 1 < N) { offsets[idx + 1] = excl + s1; cursor[idx + 1] = excl + s1; }
  if (idx + 2 < N) { offsets[idx + 2] = excl + s2; cursor[idx + 2] = excl + s2; }
  if (idx + 3 < N) { offsets[idx + 3] = excl + s3; cursor[idx + 3] = excl + s3; }
}

__global__ __launch_bounds__(256) void scatter_kernel(const int* __restrict__ e32,
                                                      const long long* __restrict__ e64,
                                                      const int* __restrict__ flag,
                                                      int* __restrict__ cursor,
                                                      int* __restrict__ csr_src,
                                                      int* __restrict__ csr_dst, int E, int N) {
  int i = blockIdx.x * 256 + threadIdx.x;
  int total = E + N;
  if (i >= total) return;
  int f = *flag;
  int src, dst;
  if (i < E) { src = edge_at(e32, e64, f, i); dst = edge_at(e32, e64, f, E + i); }
  else       { src = i - E; dst = src; }
  int pos = atomicAdd(&cursor[dst], 1);
  csr_src[pos] = src;
  csr_dst[pos] = dst;
}

// ---------------------------------------------------------------------------
// fp32 -> bf16 elementwise (n divisible by 4)
__global__ __launch_bounds__(256) void cvt_x_kernel(const float* __restrict__ in,
                                                    unsigned short* __restrict__ out, long n4) {
  long i = (long)blockIdx.x * 256 + threadIdx.x;
  if (i >= n4) return;
  float4 v = *(const float4*)&in[i * 4];
  ushort4 o;
  o.x = f2b(v.x); o.y = f2b(v.y); o.z = f2b(v.z); o.w = f2b(v.w);
  *(ushort4*)&out[i * 4] = o;
}

// W[K][512] fp32 -> Wt[512][K] bf16 (tiny)
__global__ __launch_bounds__(256) void cvt_w_kernel(const float* __restrict__ W,
                                                    unsigned short* __restrict__ Wt, int K) {
  int idx = blockIdx.x * 256 + threadIdx.x;
  if (idx >= K * F_OUT) return;
  int k = idx / F_OUT, c = idx % F_OUT;
  Wt[c * K + k] = f2b(W[idx]);
}

// ---------------------------------------------------------------------------
// bf16 MFMA GEMM: C[M,512](bf16) = A[M,K](bf16) @ Bt[512,K](bf16)^T
// 128x128 tile, 4 waves (2x2), 4x4 16x16x32 fragments per wave, BK=32.
#define LDK 40  // padded LDS K-stride (bf16 elems)
__global__ __launch_bounds__(256) void gemm_bf16_kernel(const unsigned short* __restrict__ A,
                                                        const unsigned short* __restrict__ Bt,
                                                        unsigned short* __restrict__ C,
                                                        int M, int K) {
  __shared__ unsigned short As[128][LDK];
  __shared__ unsigned short Bs[128][LDK];
  int tid = threadIdx.x;
  int lane = tid & 63, wid = tid >> 6;
  int wr = wid >> 1, wc = wid & 1;
  int rowBase = blockIdx.x * 128, colBase = blockIdx.y * 128;
  f32x4 acc[4][4];
#pragma unroll
  for (int i = 0; i < 4; i++)
#pragma unroll
    for (int j = 0; j < 4; j++) acc[i][j] = (f32x4){0.f, 0.f, 0.f, 0.f};

  int fr = lane & 15, fk = (lane >> 4) * 8;

  for (int k0 = 0; k0 < K; k0 += 32) {
#pragma unroll
    for (int i = 0; i < 2; i++) {
      int idx = i * 256 + tid;
      int r = idx >> 2, cq = (idx & 3) * 8;
      int gr = rowBase + r;
      float4 va = make_float4(0.f, 0.f, 0.f, 0.f);
      if (gr < M) va = *(const float4*)&A[(size_t)gr * K + k0 + cq];
      *(float4*)&As[r][cq] = va;
      *(float4*)&Bs[r][cq] = *(const float4*)&Bt[(size_t)(colBase + r) * K + k0 + cq];
    }
    __syncthreads();
    bf16x8 af[4], bfv[4];
#pragma unroll
    for (int mi = 0; mi < 4; mi++)
      af[mi] = *(const bf16x8*)&As[wr * 64 + mi * 16 + fr][fk];
#pragma unroll
    for (int ni = 0; ni < 4; ni++)
      bfv[ni] = *(const bf16x8*)&Bs[wc * 64 + ni * 16 + fr][fk];
#pragma unroll
    for (int mi = 0; mi < 4; mi++)
#pragma unroll
      for (int ni = 0; ni < 4; ni++)
        acc[mi][ni] = __builtin_amdgcn_mfma_f32_16x16x32_bf16(af[mi], bfv[ni], acc[mi][ni], 0, 0, 0);
    __syncthreads();
  }
  int r0 = rowBase + wr * 64, c0 = colBase + wc * 64;
#pragma unroll
  for (int mi = 0; mi < 4; mi++) {
#pragma unroll
    for (int ni = 0; ni < 4; ni++) {
      int col = c0 + ni * 16 + (lane & 15);
#pragma unroll
      for (int q = 0; q < 4; q++) {
        int row = r0 + mi * 16 + (lane >> 4) * 4 + q;
        if (row < M) C[(size_t)row * F_OUT + col] = f2b(acc[mi][ni][q]);
      }
    }
  }
}

// ---------------------------------------------------------------------------
// attdot: wave = node (grid-stride); 16-lane group = head; ushort8 row loads.
__global__ __launch_bounds__(256) void attdot_kernel(const unsigned short* __restrict__ h,
                                                     const float* __restrict__ att_s,
                                                     const float* __restrict__ att_d,
                                                     float* __restrict__ a_s,
                                                     float* __restrict__ a_d, int N) {
  int lane = threadIdx.x & 63;
  int hh = lane >> 4, sl = lane & 15;
  int gwave = (blockIdx.x * 256 + threadIdx.x) >> 6;
  int nwaves = (gridDim.x * 256) >> 6;
  float asv[8], adv[8];
#pragma unroll
  for (int j = 0; j < 8; j++) {
    asv[j] = att_s[hh * HID + sl * 8 + j];
    adv[j] = att_d[hh * HID + sl * 8 + j];
  }
  for (int n = gwave; n < N; n += nwaves) {
    bf16x8 hv = *(const bf16x8*)&h[(size_t)n * F_OUT + hh * HID + sl * 8];
    float s = 0.f, d = 0.f;
#pragma unroll
    for (int j = 0; j < 8; j++) {
      float f = bf2f((unsigned short)hv[j]);
      s += f * asv[j];
      d += f * adv[j];
    }
#pragma unroll
    for (int off = 1; off < 16; off <<= 1) {
      s += __shfl_xor(s, off);
      d += __shfl_xor(d, off);
    }
    if (sl == 0) {
      a_s[n * HEADS + hh] = s;
      a_d[n * HEADS + hh] = d;
    }
  }
}

// ---------------------------------------------------------------------------
// edge-parallel raw attention: alpha[i*4+h] = leaky(a_s[src]+a_d[dst])
__global__ __launch_bounds__(256) void alpha_kernel(const int* __restrict__ csr_src,
                                                    const int* __restrict__ csr_dst,
                                                    const float* __restrict__ a_s,
                                                    const float* __restrict__ a_d,
                                                    float* __restrict__ alpha, int Etot) {
  int t = blockIdx.x * 256 + threadIdx.x;
  if (t >= Etot * HEADS) return;
  int i = t >> 2, hh = t & 3;
  int s = csr_src[i], d = csr_dst[i];
  float al = a_s[s * HEADS + hh] + a_d[d * HEADS + hh];
  al = (al > 0.f) ? al : al * NEG_SLOPE;
  alpha[t] = al;
}

// ---------------------------------------------------------------------------
// per-(node,head): segment softmax over alpha -> normalized weights in place
__global__ __launch_bounds__(256) void norm_kernel(const int* __restrict__ offsets,
                                                   float* __restrict__ alpha, int N) {
  int t = blockIdx.x * 256 + threadIdx.x;
  if (t >= N * HEADS) return;
  int n = t >> 2, hh = t & 3;
  int beg = offsets[n], end = offsets[n + 1];
  float m = -1e30f;
  for (int i = beg; i < end; i++) m = fmaxf(m, alpha[i * HEADS + hh]);
  float denom = 0.f;
  for (int i = beg; i < end; i++) {
    float ex = __expf(alpha[i * HEADS + hh] - m);
    alpha[i * HEADS + hh] = ex;
    denom += ex;
  }
  float inv = 1.f / (denom + GAT_EPS);
  for (int i = beg; i < end; i++) alpha[i * HEADS + hh] *= inv;
}

// ---------------------------------------------------------------------------
// aggregate: block = node, wave = head, 4 edge-slots x 16 lanes; ushort8 rows.
// OUT_BF=1 -> bf16 out (layer-1 intermediate), else fp32 (final).
template <int OUT_BF>
__global__ __launch_bounds__(256) void aggregate_kernel(const unsigned short* __restrict__ h,
                                                        const float* __restrict__ wexp,
                                                        const int* __restrict__ offsets,
                                                        const int* __restrict__ csr_src,
                                                        const float* __restrict__ bias,
                                                        void* __restrict__ out, int N) {
  int n = blockIdx.x;
  int w = threadIdx.x >> 6;      // head
  int lane = threadIdx.x & 63;
  int slot = lane >> 4, sl = lane & 15;
  int beg = offsets[n], end = offsets[n + 1];

  float acc[8];
#pragma unroll
  for (int j = 0; j < 8; j++) acc[j] = 0.f;

  int e = beg + slot;
  int s = 0; float wgt = 0.f;
  if (e < end) { s = csr_src[e]; wgt = wexp[e * HEADS + w]; }
  while (e < end) {
    int ne = e + 4;
    int ns = 0; float nw = 0.f;
    if (ne < end) { ns = csr_src[ne]; nw = wexp[ne * HEADS + w]; }
    bf16x8 hv = *(const bf16x8*)&h[(size_t)s * F_OUT + w * HID + sl * 8];
#pragma unroll
    for (int j = 0; j < 8; j++) acc[j] += bf2f((unsigned short)hv[j]) * wgt;
    e = ne; s = ns; wgt = nw;
  }
#pragma unroll
  for (int j = 0; j < 8; j++) {
    acc[j] += __shfl_xor(acc[j], 16);
    acc[j] += __shfl_xor(acc[j], 32);
  }

  __shared__ float red[HEADS][HID];
  if (slot == 0) {
#pragma unroll
    for (int j = 0; j < 8; j++) red[w][sl * 8 + j] = acc[j];
  }
  __syncthreads();
  if (threadIdx.x < HID) {
    int c = threadIdx.x;
    float v = (red[0][c] + red[1][c] + red[2][c] + red[3][c]) * 0.25f + bias[c];
    v = fmaxf(v, 0.f);  // both layers end in relu
    if (OUT_BF)
      ((unsigned short*)out)[(size_t)n * HID + c] = f2b(v);
    else
      ((float*)out)[(size_t)n * HID + c] = v;
  }
}

// ---------------------------------------------------------------------------
extern "C" void kernel_launch(void* const* d_in, const int* in_sizes, int n_in,
                              void* d_out, int out_size, void* d_ws, size_t ws_size,
                              hipStream_t stream) {
  const float* x   = (const float*)d_in[0];
  const int* e32   = (const int*)d_in[1];
  const long long* e64 = (const long long*)d_in[1];
  const float* W1  = (const float*)d_in[2];
  const float* as1 = (const float*)d_in[3];
  const float* ad1 = (const float*)d_in[4];
  const float* b1  = (const float*)d_in[5];
  const float* W2  = (const float*)d_in[6];
  const float* as2 = (const float*)d_in[7];
  const float* ad2 = (const float*)d_in[8];
  const float* b2  = (const float*)d_in[9];

  int F_in = in_sizes[2] / F_OUT;       // 256
  int N = in_sizes[0] / F_in;           // 50000
  int E = in_sizes[1] / 2;              // 400000
  int Etot = E + N;

  char* ws = (char*)d_ws;
  size_t off = 0;
  auto alloc = [&](size_t bytes) -> void* {
    void* p = ws + off;
    off = (off + bytes + 255) & ~(size_t)255;
    return p;
  };
  unsigned short* h_bf   = (unsigned short*)alloc((size_t)N * F_OUT * 2);  // 51.2 MB
  unsigned short* x_bf   = (unsigned short*)alloc((size_t)N * F_in * 2);   // 25.6 MB
  unsigned short* out1_bf= (unsigned short*)alloc((size_t)N * HID * 2);    // 12.8 MB
  unsigned short* Wt1    = (unsigned short*)alloc((size_t)F_in * F_OUT * 2);
  unsigned short* Wt2    = (unsigned short*)alloc((size_t)HID * F_OUT * 2);
  float* a_s    = (float*)alloc((size_t)N * HEADS * 4);
  float* a_d    = (float*)alloc((size_t)N * HEADS * 4);
  float* alpha  = (float*)alloc((size_t)Etot * HEADS * 4);                 // 7.2 MB
  int* counts   = (int*)alloc((size_t)(N + 1) * 4);
  int* offsets  = (int*)alloc((size_t)(N + 1) * 4);
  int* cursor   = (int*)alloc((size_t)N * 4);
  int* csr_src  = (int*)alloc((size_t)Etot * 4);
  int* csr_dst  = (int*)alloc((size_t)Etot * 4);
  int* partials = (int*)alloc(1024 * 4);
  int* flag     = (int*)alloc(256);
  if (off > ws_size) return;

  int nchunks = (N + 1023) / 1024;

  hipMemsetAsync(counts, 0, (size_t)N * 4, stream);
  detect_i64_kernel<<<1, 256, 0, stream>>>((const unsigned int*)d_in[1], flag);
  hist_kernel<<<(Etot + 255) / 256, 256, 0, stream>>>(e32, e64, flag, counts, E, N);
  scan_partial_kernel<<<nchunks, 256, 0, stream>>>(counts, partials, N);
  scan_base_kernel<<<1, 256, 0, stream>>>(partials, offsets, nchunks, N);
  scan_final_kernel<<<nchunks, 256, 0, stream>>>(counts, partials, offsets, cursor, N);
  scatter_kernel<<<(Etot + 255) / 256, 256, 0, stream>>>(e32, e64, flag, cursor, csr_src, csr_dst, E, N);

  long n4x = (long)N * F_in / 4;
  cvt_x_kernel<<<(int)((n4x + 255) / 256), 256, 0, stream>>>(x, x_bf, n4x);
  cvt_w_kernel<<<(F_in * F_OUT + 255) / 256, 256, 0, stream>>>(W1, Wt1, F_in);
  cvt_w_kernel<<<(HID * F_OUT + 255) / 256, 256, 0, stream>>>(W2, Wt2, HID);

  dim3 ggrid((N + 127) / 128, F_OUT / 128);
  int ablocks = (Etot * HEADS + 255) / 256;
  int nblocks = (N * HEADS + 255) / 256;
  // ---- layer 1 ----
  gemm_bf16_kernel<<<ggrid, 256, 0, stream>>>(x_bf, Wt1, h_bf, N, F_in);
  attdot_kernel<<<512, 256, 0, stream>>>(h_bf, as1, ad1, a_s, a_d, N);
  alpha_kernel<<<ablocks, 256, 0, stream>>>(csr_src, csr_dst, a_s, a_d, alpha, Etot);
  norm_kernel<<<nblocks, 256, 0, stream>>>(offsets, alpha, N);
  aggregate_kernel<1><<<N, 256, 0, stream>>>(h_bf, alpha, offsets, csr_src, b1, out1_bf, N);
  // ---- layer 2 ----
  gemm_bf16_kernel<<<ggrid, 256, 0, stream>>>(out1_bf, Wt2, h_bf, N, HID);
  attdot_kernel<<<512, 256, 0, stream>>>(h_bf, as2, ad2, a_s, a_d, N);
  alpha_kernel<<<ablocks, 256, 0, stream>>>(csr_src, csr_dst, a_s, a_d, alpha, Etot);
  norm_kernel<<<nblocks, 256, 0, stream>>>(offsets, alpha, N);
  aggregate_kernel<0><<<N, 256, 0, stream>>>(h_bf, alpha, offsets, csr_src, b2, d_out, N);
}

// Round 5
// 358.434 us; speedup vs baseline: 2.3471x; 1.0575x over previous
//
#include <hip/hip_runtime.h>
#include <hip/hip_bf16.h>
#include <cstdint>

#define HEADS 4
#define HID 128
#define F_OUT 512   // HEADS*HID
#define NEG_SLOPE 0.2f
#define GAT_EPS 1e-16f

typedef __attribute__((ext_vector_type(8))) short bf16x8;
typedef __attribute__((ext_vector_type(4))) float f32x4;

__device__ __forceinline__ float bf2f(unsigned short u) {
  unsigned int x = ((unsigned int)u) << 16;
  return __builtin_bit_cast(float, x);
}
__device__ __forceinline__ unsigned short f2b(float f) {
  unsigned int u = __builtin_bit_cast(unsigned int, f);
  unsigned int r = (u + 0x7fffu + ((u >> 16) & 1u)) >> 16;  // RNE
  return (unsigned short)r;
}

// ---------------------------------------------------------------------------
// edge_index dtype detection (reference says int64; JAX w/o x64 ships int32).
__global__ __launch_bounds__(256) void detect_i64_kernel(const unsigned int* __restrict__ e,
                                                         int* __restrict__ flag) {
  __shared__ int nz;
  if (threadIdx.x == 0) nz = 0;
  __syncthreads();
  for (int i = threadIdx.x; i < 2048; i += blockDim.x) {
    if (e[2 * i + 1] != 0u) atomicOr(&nz, 1);
  }
  __syncthreads();
  if (threadIdx.x == 0) *flag = (nz == 0) ? 1 : 0;
}

__device__ __forceinline__ int edge_at(const int* __restrict__ e32,
                                       const long long* __restrict__ e64,
                                       int f, int i) {
  return f ? (int)e64[i] : e32[i];
}

// ---------------------------------------------------------------------------
// CSR build by dst (edges 0..E-1 from edge_index, E..E+N-1 are self loops)
__global__ __launch_bounds__(256) void hist_kernel(const int* __restrict__ e32,
                                                   const long long* __restrict__ e64,
                                                   const int* __restrict__ flag,
                                                   int* __restrict__ counts, int E, int N) {
  int i = blockIdx.x * 256 + threadIdx.x;
  int total = E + N;
  if (i >= total) return;
  int f = *flag;
  int dst = (i < E) ? edge_at(e32, e64, f, E + i) : (i - E);
  atomicAdd(&counts[dst], 1);
}

// ---- multi-block exclusive scan over counts[0..N) -> offsets, cursor -------
__global__ __launch_bounds__(256) void scan_partial_kernel(const int* __restrict__ counts,
                                                           int* __restrict__ partials, int N) {
  int t = threadIdx.x;
  int lane = t & 63, wv = t >> 6;
  int idx = blockIdx.x * 1024 + t * 4;
  int4 v = make_int4(0, 0, 0, 0);
  if (idx + 3 < N) v = *(const int4*)&counts[idx];
  else {
    if (idx + 0 < N) v.x = counts[idx + 0];
    if (idx + 1 < N) v.y = counts[idx + 1];
    if (idx + 2 < N) v.z = counts[idx + 2];
  }
  int s = v.x + v.y + v.z + v.w;
#pragma unroll
  for (int off = 32; off > 0; off >>= 1) s += __shfl_xor(s, off);
  __shared__ int wsum[4];
  if (lane == 0) wsum[wv] = s;
  __syncthreads();
  if (t == 0) partials[blockIdx.x] = wsum[0] + wsum[1] + wsum[2] + wsum[3];
}

__global__ __launch_bounds__(256) void scan_base_kernel(int* __restrict__ partials,
                                                        int* __restrict__ offsets,
                                                        int nblocks, int N) {
  __shared__ int buf[1024];
  int t = threadIdx.x;
  for (int i = t; i < nblocks; i += 256) buf[i] = partials[i];
  __syncthreads();
  if (t == 0) {
    int run = 0;
    for (int i = 0; i < nblocks; i++) { int c = buf[i]; buf[i] = run; run += c; }
    offsets[N] = run;
  }
  __syncthreads();
  for (int i = t; i < nblocks; i += 256) partials[i] = buf[i];
}

__global__ __launch_bounds__(256) void scan_final_kernel(const int* __restrict__ counts,
                                                         const int* __restrict__ partials,
                                                         int* __restrict__ offsets,
                                                         int* __restrict__ cursor, int N) {
  int t = threadIdx.x;
  int lane = t & 63, wv = t >> 6;
  int idx = blockIdx.x * 1024 + t * 4;
  int4 v = make_int4(0, 0, 0, 0);
  if (idx + 3 < N) v = *(const int4*)&counts[idx];
  else {
    if (idx + 0 < N) v.x = counts[idx + 0];
    if (idx + 1 < N) v.y = counts[idx + 1];
    if (idx + 2 < N) v.z = counts[idx + 2];
  }
  int s1 = v.x, s2 = s1 + v.y, s3 = s2 + v.z, s4 = s3 + v.w;
  int val = s4;
#pragma unroll
  for (int off = 1; off < 64; off <<= 1) {
    int y = __shfl_up(val, off);
    if (lane >= off) val += y;
  }
  __shared__ int wsum[4];
  if (lane == 63) wsum[wv] = val;
  __syncthreads();
  int wbase = 0;
  for (int i = 0; i < wv; i++) wbase += wsum[i];
  int excl = partials[blockIdx.x] + wbase + (val - s4);
  if (idx + 0 < N) { offsets[idx + 0] = excl;      cursor[idx + 0] = excl; }
  if (idx + 1 < N) { offsets[idx + 1] = excl + s1; cursor[idx + 1] = excl + s1; }
  if (idx + 2 < N) { offsets[idx + 2] = excl + s2; cursor[idx + 2] = excl + s2; }
  if (idx + 3 < N) { offsets[idx + 3] = excl + s3; cursor[idx + 3] = excl + s3; }
}

__global__ __launch_bounds__(256) void scatter_kernel(const int* __restrict__ e32,
                                                      const long long* __restrict__ e64,
                                                      const int* __restrict__ flag,
                                                      int* __restrict__ cursor,
                                                      int* __restrict__ csr_src, int E, int N) {
  int i = blockIdx.x * 256 + threadIdx.x;
  int total = E + N;
  if (i >= total) return;
  int f = *flag;
  int src, dst;
  if (i < E) { src = edge_at(e32, e64, f, i); dst = edge_at(e32, e64, f, E + i); }
  else       { src = i - E; dst = src; }
  int pos = atomicAdd(&cursor[dst], 1);
  csr_src[pos] = src;
}

// ---------------------------------------------------------------------------
// W[K][512] fp32 -> Wt[512][K] bf16 (tiny)
__global__ __launch_bounds__(256) void cvt_w_kernel(const float* __restrict__ W,
                                                    unsigned short* __restrict__ Wt, int K) {
  int idx = blockIdx.x * 256 + threadIdx.x;
  if (idx >= K * F_OUT) return;
  int k = idx / F_OUT, c = idx % F_OUT;
  Wt[c * K + k] = f2b(W[idx]);
}

// ---------------------------------------------------------------------------
// Fused bf16 MFMA GEMM + attention dots.
// C[M,512](bf16) = A[M,K] @ Bt[512,K]^T ; AF32: A is fp32 (converted inline).
// Tile 128x128; grid.y = head (128 cols == one head). Epilogue also computes
// a_s[row,head] = sum_c h*att_src, a_d likewise, from fp32 accumulators.
#define LDK 40  // padded LDS K-stride (bf16 elems)
template <int AF32>
__global__ __launch_bounds__(256) void gemm_att_kernel(const void* __restrict__ Araw,
                                                       const unsigned short* __restrict__ Bt,
                                                       unsigned short* __restrict__ C,
                                                       const float* __restrict__ att_s,
                                                       const float* __restrict__ att_d,
                                                       float* __restrict__ a_s,
                                                       float* __restrict__ a_d,
                                                       int M, int K) {
  __shared__ unsigned short As[128][LDK];
  __shared__ unsigned short Bs[128][LDK];
  __shared__ float sred[2][128];
  __shared__ float dred[2][128];
  int tid = threadIdx.x;
  int lane = tid & 63, wid = tid >> 6;
  int wr = wid >> 1, wc = wid & 1;
  int head = blockIdx.y;
  int rowBase = blockIdx.x * 128, colBase = head * 128;
  f32x4 acc[4][4];
#pragma unroll
  for (int i = 0; i < 4; i++)
#pragma unroll
    for (int j = 0; j < 4; j++) acc[i][j] = (f32x4){0.f, 0.f, 0.f, 0.f};

  int fr = lane & 15, fk = (lane >> 4) * 8;

  for (int k0 = 0; k0 < K; k0 += 32) {
#pragma unroll
    for (int i = 0; i < 2; i++) {
      int idx = i * 256 + tid;
      int r = idx >> 2, cq = (idx & 3) * 8;
      int gr = rowBase + r;
      if (AF32) {
        const float* Af = (const float*)Araw;
        float4 v0 = make_float4(0.f, 0.f, 0.f, 0.f), v1 = v0;
        if (gr < M) {
          v0 = *(const float4*)&Af[(size_t)gr * K + k0 + cq];
          v1 = *(const float4*)&Af[(size_t)gr * K + k0 + cq + 4];
        }
        bf16x8 o;
        o[0] = (short)f2b(v0.x); o[1] = (short)f2b(v0.y);
        o[2] = (short)f2b(v0.z); o[3] = (short)f2b(v0.w);
        o[4] = (short)f2b(v1.x); o[5] = (short)f2b(v1.y);
        o[6] = (short)f2b(v1.z); o[7] = (short)f2b(v1.w);
        *(bf16x8*)&As[r][cq] = o;
      } else {
        const unsigned short* Ab = (const unsigned short*)Araw;
        float4 va = make_float4(0.f, 0.f, 0.f, 0.f);
        if (gr < M) va = *(const float4*)&Ab[(size_t)gr * K + k0 + cq];
        *(float4*)&As[r][cq] = va;
      }
      *(float4*)&Bs[r][cq] = *(const float4*)&Bt[(size_t)(colBase + r) * K + k0 + cq];
    }
    __syncthreads();
    bf16x8 af[4], bfv[4];
#pragma unroll
    for (int mi = 0; mi < 4; mi++)
      af[mi] = *(const bf16x8*)&As[wr * 64 + mi * 16 + fr][fk];
#pragma unroll
    for (int ni = 0; ni < 4; ni++)
      bfv[ni] = *(const bf16x8*)&Bs[wc * 64 + ni * 16 + fr][fk];
#pragma unroll
    for (int mi = 0; mi < 4; mi++)
#pragma unroll
      for (int ni = 0; ni < 4; ni++)
        acc[mi][ni] = __builtin_amdgcn_mfma_f32_16x16x32_bf16(af[mi], bfv[ni], acc[mi][ni], 0, 0, 0);
    __syncthreads();
  }

  // ---- C store (C/D layout: col=lane&15, row=(lane>>4)*4+q) ----
  int r0 = rowBase + wr * 64, c0 = colBase + wc * 64;
#pragma unroll
  for (int mi = 0; mi < 4; mi++) {
#pragma unroll
    for (int ni = 0; ni < 4; ni++) {
      int col = c0 + ni * 16 + (lane & 15);
#pragma unroll
      for (int q = 0; q < 4; q++) {
        int row = r0 + mi * 16 + (lane >> 4) * 4 + q;
        if (row < M) C[(size_t)row * F_OUT + col] = f2b(acc[mi][ni][q]);
      }
    }
  }

  // ---- fused attention dots ----
  float asv[4], adv[4];
#pragma unroll
  for (int ni = 0; ni < 4; ni++) {
    int cih = wc * 64 + ni * 16 + (lane & 15);  // col within head
    asv[ni] = att_s[head * HID + cih];
    adv[ni] = att_d[head * HID + cih];
  }
#pragma unroll
  for (int mi = 0; mi < 4; mi++) {
#pragma unroll
    for (int q = 0; q < 4; q++) {
      float ps = 0.f, pd = 0.f;
#pragma unroll
      for (int ni = 0; ni < 4; ni++) {
        ps += acc[mi][ni][q] * asv[ni];
        pd += acc[mi][ni][q] * adv[ni];
      }
#pragma unroll
      for (int off = 1; off < 16; off <<= 1) {
        ps += __shfl_xor(ps, off);
        pd += __shfl_xor(pd, off);
      }
      if ((lane & 15) == 0) {
        int rl = wr * 64 + mi * 16 + (lane >> 4) * 4 + q;
        sred[wc][rl] = ps;
        dred[wc][rl] = pd;
      }
    }
  }
  __syncthreads();
  if (tid < 128) {
    int row = rowBase + tid;
    if (row < M) {
      a_s[row * HEADS + head] = sred[0][tid] + sred[1][tid];
      a_d[row * HEADS + head] = dred[0][tid] + dred[1][tid];
    }
  }
}

// ---------------------------------------------------------------------------
// fused alpha+softmax per (node,head): gather a_s[src]+a_d[n], leaky, softmax
// -> normalized weights in alpha[edge*HEADS+h]
__global__ __launch_bounds__(256) void norm_kernel(const int* __restrict__ offsets,
                                                   const int* __restrict__ csr_src,
                                                   const float* __restrict__ a_s,
                                                   const float* __restrict__ a_d,
                                                   float* __restrict__ alpha, int N) {
  int t = blockIdx.x * 256 + threadIdx.x;
  if (t >= N * HEADS) return;
  int n = t >> 2, hh = t & 3;
  int beg = offsets[n], end = offsets[n + 1];
  float adn = a_d[n * HEADS + hh];
  float m = -1e30f;
  for (int i = beg; i < end; i++) {
    float al = a_s[csr_src[i] * HEADS + hh] + adn;
    al = (al > 0.f) ? al : al * NEG_SLOPE;
    alpha[i * HEADS + hh] = al;
    m = fmaxf(m, al);
  }
  float denom = 0.f;
  for (int i = beg; i < end; i++) {
    float ex = __expf(alpha[i * HEADS + hh] - m);
    alpha[i * HEADS + hh] = ex;
    denom += ex;
  }
  float inv = 1.f / (denom + GAT_EPS);
  for (int i = beg; i < end; i++) alpha[i * HEADS + hh] *= inv;
}

// ---------------------------------------------------------------------------
// aggregate: block = node, wave = head, 4 edge-slots x 16 lanes; ushort8 rows.
template <int OUT_BF>
__global__ __launch_bounds__(256) void aggregate_kernel(const unsigned short* __restrict__ h,
                                                        const float* __restrict__ wexp,
                                                        const int* __restrict__ offsets,
                                                        const int* __restrict__ csr_src,
                                                        const float* __restrict__ bias,
                                                        void* __restrict__ out, int N) {
  int n = blockIdx.x;
  int w = threadIdx.x >> 6;      // head
  int lane = threadIdx.x & 63;
  int slot = lane >> 4, sl = lane & 15;
  int beg = offsets[n], end = offsets[n + 1];

  float acc[8];
#pragma unroll
  for (int j = 0; j < 8; j++) acc[j] = 0.f;

  int e = beg + slot;
  int s = 0; float wgt = 0.f;
  if (e < end) { s = csr_src[e]; wgt = wexp[e * HEADS + w]; }
  while (e < end) {
    int ne = e + 4;
    int ns = 0; float nw = 0.f;
    if (ne < end) { ns = csr_src[ne]; nw = wexp[ne * HEADS + w]; }
    bf16x8 hv = *(const bf16x8*)&h[(size_t)s * F_OUT + w * HID + sl * 8];
#pragma unroll
    for (int j = 0; j < 8; j++) acc[j] += bf2f((unsigned short)hv[j]) * wgt;
    e = ne; s = ns; wgt = nw;
  }
#pragma unroll
  for (int j = 0; j < 8; j++) {
    acc[j] += __shfl_xor(acc[j], 16);
    acc[j] += __shfl_xor(acc[j], 32);
  }

  __shared__ float red[HEADS][HID];
  if (slot == 0) {
#pragma unroll
    for (int j = 0; j < 8; j++) red[w][sl * 8 + j] = acc[j];
  }
  __syncthreads();
  if (threadIdx.x < HID) {
    int c = threadIdx.x;
    float v = (red[0][c] + red[1][c] + red[2][c] + red[3][c]) * 0.25f + bias[c];
    v = fmaxf(v, 0.f);  // both layers end in relu
    if (OUT_BF)
      ((unsigned short*)out)[(size_t)n * HID + c] = f2b(v);
    else
      ((float*)out)[(size_t)n * HID + c] = v;
  }
}

// ---------------------------------------------------------------------------
extern "C" void kernel_launch(void* const* d_in, const int* in_sizes, int n_in,
                              void* d_out, int out_size, void* d_ws, size_t ws_size,
                              hipStream_t stream) {
  const float* x   = (const float*)d_in[0];
  const int* e32   = (const int*)d_in[1];
  const long long* e64 = (const long long*)d_in[1];
  const float* W1  = (const float*)d_in[2];
  const float* as1 = (const float*)d_in[3];
  const float* ad1 = (const float*)d_in[4];
  const float* b1  = (const float*)d_in[5];
  const float* W2  = (const float*)d_in[6];
  const float* as2 = (const float*)d_in[7];
  const float* ad2 = (const float*)d_in[8];
  const float* b2  = (const float*)d_in[9];

  int F_in = in_sizes[2] / F_OUT;       // 256
  int N = in_sizes[0] / F_in;           // 50000
  int E = in_sizes[1] / 2;              // 400000
  int Etot = E + N;

  char* ws = (char*)d_ws;
  size_t off = 0;
  auto alloc = [&](size_t bytes) -> void* {
    void* p = ws + off;
    off = (off + bytes + 255) & ~(size_t)255;
    return p;
  };
  unsigned short* h_bf   = (unsigned short*)alloc((size_t)N * F_OUT * 2);  // 51.2 MB
  unsigned short* out1_bf= (unsigned short*)alloc((size_t)N * HID * 2);    // 12.8 MB
  unsigned short* Wt1    = (unsigned short*)alloc((size_t)F_in * F_OUT * 2);
  unsigned short* Wt2    = (unsigned short*)alloc((size_t)HID * F_OUT * 2);
  float* a_s    = (float*)alloc((size_t)N * HEADS * 4);
  float* a_d    = (float*)alloc((size_t)N * HEADS * 4);
  float* alpha  = (float*)alloc((size_t)Etot * HEADS * 4);                 // 7.2 MB
  int* counts   = (int*)alloc((size_t)(N + 1) * 4);
  int* offsets  = (int*)alloc((size_t)(N + 1) * 4);
  int* cursor   = (int*)alloc((size_t)N * 4);
  int* csr_src  = (int*)alloc((size_t)Etot * 4);
  int* partials = (int*)alloc(1024 * 4);
  int* flag     = (int*)alloc(256);
  if (off > ws_size) return;

  int nchunks = (N + 1023) / 1024;

  hipMemsetAsync(counts, 0, (size_t)N * 4, stream);
  detect_i64_kernel<<<1, 256, 0, stream>>>((const unsigned int*)d_in[1], flag);
  hist_kernel<<<(Etot + 255) / 256, 256, 0, stream>>>(e32, e64, flag, counts, E, N);
  scan_partial_kernel<<<nchunks, 256, 0, stream>>>(counts, partials, N);
  scan_base_kernel<<<1, 256, 0, stream>>>(partials, offsets, nchunks, N);
  scan_final_kernel<<<nchunks, 256, 0, stream>>>(counts, partials, offsets, cursor, N);
  scatter_kernel<<<(Etot + 255) / 256, 256, 0, stream>>>(e32, e64, flag, cursor, csr_src, E, N);

  cvt_w_kernel<<<(F_in * F_OUT + 255) / 256, 256, 0, stream>>>(W1, Wt1, F_in);
  cvt_w_kernel<<<(HID * F_OUT + 255) / 256, 256, 0, stream>>>(W2, Wt2, HID);

  dim3 ggrid((N + 127) / 128, HEADS);
  int nblocks = (N * HEADS + 255) / 256;
  // ---- layer 1 ----
  gemm_att_kernel<1><<<ggrid, 256, 0, stream>>>(x, Wt1, h_bf, as1, ad1, a_s, a_d, N, F_in);
  norm_kernel<<<nblocks, 256, 0, stream>>>(offsets, csr_src, a_s, a_d, alpha, N);
  aggregate_kernel<1><<<N, 256, 0, stream>>>(h_bf, alpha, offsets, csr_src, b1, out1_bf, N);
  // ---- layer 2 ----
  gemm_att_kernel<0><<<ggrid, 256, 0, stream>>>(out1_bf, Wt2, h_bf, as2, ad2, a_s, a_d, N, HID);
  norm_kernel<<<nblocks, 256, 0, stream>>>(offsets, csr_src, a_s, a_d, alpha, N);
  aggregate_kernel<0><<<N, 256, 0, stream>>>(h_bf, alpha, offsets, csr_src, b2, d_out, N);
}

// Round 6
// 353.786 us; speedup vs baseline: 2.3779x; 1.0131x over previous
//
#include <hip/hip_runtime.h>
#include <hip/hip_bf16.h>
#include <cstdint>

#define HEADS 4
#define HID 128
#define F_OUT 512   // HEADS*HID
#define NEG_SLOPE 0.2f
#define GAT_EPS 1e-16f

typedef __attribute__((ext_vector_type(8))) short bf16x8;
typedef __attribute__((ext_vector_type(4))) float f32x4;

__device__ __forceinline__ float bf2f(unsigned short u) {
  unsigned int x = ((unsigned int)u) << 16;
  return __builtin_bit_cast(float, x);
}
__device__ __forceinline__ unsigned short f2b(float f) {
  unsigned int u = __builtin_bit_cast(unsigned int, f);
  unsigned int r = (u + 0x7fffu + ((u >> 16) & 1u)) >> 16;  // RNE
  return (unsigned short)r;
}

// ---------------------------------------------------------------------------
// edge_index dtype detection (reference says int64; JAX w/o x64 ships int32).
__global__ __launch_bounds__(256) void detect_i64_kernel(const unsigned int* __restrict__ e,
                                                         int* __restrict__ flag) {
  __shared__ int nz;
  if (threadIdx.x == 0) nz = 0;
  __syncthreads();
  for (int i = threadIdx.x; i < 2048; i += blockDim.x) {
    if (e[2 * i + 1] != 0u) atomicOr(&nz, 1);
  }
  __syncthreads();
  if (threadIdx.x == 0) *flag = (nz == 0) ? 1 : 0;
}

__device__ __forceinline__ int edge_at(const int* __restrict__ e32,
                                       const long long* __restrict__ e64,
                                       int f, int i) {
  return f ? (int)e64[i] : e32[i];
}

// ---------------------------------------------------------------------------
// CSR build by dst (edges 0..E-1 from edge_index, E..E+N-1 are self loops)
__global__ __launch_bounds__(256) void hist_kernel(const int* __restrict__ e32,
                                                   const long long* __restrict__ e64,
                                                   const int* __restrict__ flag,
                                                   int* __restrict__ counts, int E, int N) {
  int i = blockIdx.x * 256 + threadIdx.x;
  int total = E + N;
  if (i >= total) return;
  int f = *flag;
  int dst = (i < E) ? edge_at(e32, e64, f, E + i) : (i - E);
  atomicAdd(&counts[dst], 1);
}

// ---- multi-block exclusive scan over counts[0..N) -> offsets, cursor -------
__global__ __launch_bounds__(256) void scan_partial_kernel(const int* __restrict__ counts,
                                                           int* __restrict__ partials, int N) {
  int t = threadIdx.x;
  int lane = t & 63, wv = t >> 6;
  int idx = blockIdx.x * 1024 + t * 4;
  int4 v = make_int4(0, 0, 0, 0);
  if (idx + 3 < N) v = *(const int4*)&counts[idx];
  else {
    if (idx + 0 < N) v.x = counts[idx + 0];
    if (idx + 1 < N) v.y = counts[idx + 1];
    if (idx + 2 < N) v.z = counts[idx + 2];
  }
  int s = v.x + v.y + v.z + v.w;
#pragma unroll
  for (int off = 32; off > 0; off >>= 1) s += __shfl_xor(s, off);
  __shared__ int wsum[4];
  if (lane == 0) wsum[wv] = s;
  __syncthreads();
  if (t == 0) partials[blockIdx.x] = wsum[0] + wsum[1] + wsum[2] + wsum[3];
}

__global__ __launch_bounds__(256) void scan_base_kernel(int* __restrict__ partials,
                                                        int* __restrict__ offsets,
                                                        int nblocks, int N) {
  __shared__ int buf[1024];
  int t = threadIdx.x;
  for (int i = t; i < nblocks; i += 256) buf[i] = partials[i];
  __syncthreads();
  if (t == 0) {
    int run = 0;
    for (int i = 0; i < nblocks; i++) { int c = buf[i]; buf[i] = run; run += c; }
    offsets[N] = run;
  }
  __syncthreads();
  for (int i = t; i < nblocks; i += 256) partials[i] = buf[i];
}

__global__ __launch_bounds__(256) void scan_final_kernel(const int* __restrict__ counts,
                                                         const int* __restrict__ partials,
                                                         int* __restrict__ offsets,
                                                         int* __restrict__ cursor, int N) {
  int t = threadIdx.x;
  int lane = t & 63, wv = t >> 6;
  int idx = blockIdx.x * 1024 + t * 4;
  int4 v = make_int4(0, 0, 0, 0);
  if (idx + 3 < N) v = *(const int4*)&counts[idx];
  else {
    if (idx + 0 < N) v.x = counts[idx + 0];
    if (idx + 1 < N) v.y = counts[idx + 1];
    if (idx + 2 < N) v.z = counts[idx + 2];
  }
  int s1 = v.x, s2 = s1 + v.y, s3 = s2 + v.z, s4 = s3 + v.w;
  int val = s4;
#pragma unroll
  for (int off = 1; off < 64; off <<= 1) {
    int y = __shfl_up(val, off);
    if (lane >= off) val += y;
  }
  __shared__ int wsum[4];
  if (lane == 63) wsum[wv] = val;
  __syncthreads();
  int wbase = 0;
  for (int i = 0; i < wv; i++) wbase += wsum[i];
  int excl = partials[blockIdx.x] + wbase + (val - s4);
  if (idx + 0 < N) { offsets[idx + 0] = excl;      cursor[idx + 0] = excl; }
  if (idx + 1 < N) { offsets[idx + 1] = excl + s1; cursor[idx + 1] = excl + s1; }
  if (idx + 2 < N) { offsets[idx + 2] = excl + s2; cursor[idx + 2] = excl + s2; }
  if (idx + 3 < N) { offsets[idx + 3] = excl + s3; cursor[idx + 3] = excl + s3; }
}

__global__ __launch_bounds__(256) void scatter_kernel(const int* __restrict__ e32,
                                                      const long long* __restrict__ e64,
                                                      const int* __restrict__ flag,
                                                      int* __restrict__ cursor,
                                                      int* __restrict__ csr_src, int E, int N) {
  int i = blockIdx.x * 256 + threadIdx.x;
  int total = E + N;
  if (i >= total) return;
  int f = *flag;
  int src, dst;
  if (i < E) { src = edge_at(e32, e64, f, i); dst = edge_at(e32, e64, f, E + i); }
  else       { src = i - E; dst = src; }
  int pos = atomicAdd(&cursor[dst], 1);
  csr_src[pos] = src;
}

// ---------------------------------------------------------------------------
// W[K][512] fp32 -> Wt[512][K] bf16 (tiny)
__global__ __launch_bounds__(256) void cvt_w_kernel(const float* __restrict__ W,
                                                    unsigned short* __restrict__ Wt, int K) {
  int idx = blockIdx.x * 256 + threadIdx.x;
  if (idx >= K * F_OUT) return;
  int k = idx / F_OUT, c = idx % F_OUT;
  Wt[c * K + k] = f2b(W[idx]);
}

// ---------------------------------------------------------------------------
// Fused bf16 MFMA GEMM + attention dots.
// C[M,512](bf16) = A[M,K] @ Bt[512,K]^T ; AF32: A is fp32 (converted inline).
// Tile 128x128; grid.y = head (128 cols == one head). Epilogue also computes
// a_s[row,head] = sum_c h*att_src, a_d likewise, from fp32 accumulators.
#define LDK 40  // padded LDS K-stride (bf16 elems)
template <int AF32>
__global__ __launch_bounds__(256) void gemm_att_kernel(const void* __restrict__ Araw,
                                                       const unsigned short* __restrict__ Bt,
                                                       unsigned short* __restrict__ C,
                                                       const float* __restrict__ att_s,
                                                       const float* __restrict__ att_d,
                                                       float* __restrict__ a_s,
                                                       float* __restrict__ a_d,
                                                       int M, int K) {
  __shared__ unsigned short As[128][LDK];
  __shared__ unsigned short Bs[128][LDK];
  __shared__ float sred[2][128];
  __shared__ float dred[2][128];
  int tid = threadIdx.x;
  int lane = tid & 63, wid = tid >> 6;
  int wr = wid >> 1, wc = wid & 1;
  int head = blockIdx.y;
  int rowBase = blockIdx.x * 128, colBase = head * 128;
  f32x4 acc[4][4];
#pragma unroll
  for (int i = 0; i < 4; i++)
#pragma unroll
    for (int j = 0; j < 4; j++) acc[i][j] = (f32x4){0.f, 0.f, 0.f, 0.f};

  int fr = lane & 15, fk = (lane >> 4) * 8;

  for (int k0 = 0; k0 < K; k0 += 32) {
#pragma unroll
    for (int i = 0; i < 2; i++) {
      int idx = i * 256 + tid;
      int r = idx >> 2, cq = (idx & 3) * 8;
      int gr = rowBase + r;
      if (AF32) {
        const float* Af = (const float*)Araw;
        float4 v0 = make_float4(0.f, 0.f, 0.f, 0.f), v1 = v0;
        if (gr < M) {
          v0 = *(const float4*)&Af[(size_t)gr * K + k0 + cq];
          v1 = *(const float4*)&Af[(size_t)gr * K + k0 + cq + 4];
        }
        bf16x8 o;
        o[0] = (short)f2b(v0.x); o[1] = (short)f2b(v0.y);
        o[2] = (short)f2b(v0.z); o[3] = (short)f2b(v0.w);
        o[4] = (short)f2b(v1.x); o[5] = (short)f2b(v1.y);
        o[6] = (short)f2b(v1.z); o[7] = (short)f2b(v1.w);
        *(bf16x8*)&As[r][cq] = o;
      } else {
        const unsigned short* Ab = (const unsigned short*)Araw;
        float4 va = make_float4(0.f, 0.f, 0.f, 0.f);
        if (gr < M) va = *(const float4*)&Ab[(size_t)gr * K + k0 + cq];
        *(float4*)&As[r][cq] = va;
      }
      *(float4*)&Bs[r][cq] = *(const float4*)&Bt[(size_t)(colBase + r) * K + k0 + cq];
    }
    __syncthreads();
    bf16x8 af[4], bfv[4];
#pragma unroll
    for (int mi = 0; mi < 4; mi++)
      af[mi] = *(const bf16x8*)&As[wr * 64 + mi * 16 + fr][fk];
#pragma unroll
    for (int ni = 0; ni < 4; ni++)
      bfv[ni] = *(const bf16x8*)&Bs[wc * 64 + ni * 16 + fr][fk];
#pragma unroll
    for (int mi = 0; mi < 4; mi++)
#pragma unroll
      for (int ni = 0; ni < 4; ni++)
        acc[mi][ni] = __builtin_amdgcn_mfma_f32_16x16x32_bf16(af[mi], bfv[ni], acc[mi][ni], 0, 0, 0);
    __syncthreads();
  }

  // ---- C store (C/D layout: col=lane&15, row=(lane>>4)*4+q) ----
  int r0 = rowBase + wr * 64, c0 = colBase + wc * 64;
#pragma unroll
  for (int mi = 0; mi < 4; mi++) {
#pragma unroll
    for (int ni = 0; ni < 4; ni++) {
      int col = c0 + ni * 16 + (lane & 15);
#pragma unroll
      for (int q = 0; q < 4; q++) {
        int row = r0 + mi * 16 + (lane >> 4) * 4 + q;
        if (row < M) C[(size_t)row * F_OUT + col] = f2b(acc[mi][ni][q]);
      }
    }
  }

  // ---- fused attention dots ----
  float asv[4], adv[4];
#pragma unroll
  for (int ni = 0; ni < 4; ni++) {
    int cih = wc * 64 + ni * 16 + (lane & 15);  // col within head
    asv[ni] = att_s[head * HID + cih];
    adv[ni] = att_d[head * HID + cih];
  }
#pragma unroll
  for (int mi = 0; mi < 4; mi++) {
#pragma unroll
    for (int q = 0; q < 4; q++) {
      float ps = 0.f, pd = 0.f;
#pragma unroll
      for (int ni = 0; ni < 4; ni++) {
        ps += acc[mi][ni][q] * asv[ni];
        pd += acc[mi][ni][q] * adv[ni];
      }
#pragma unroll
      for (int off = 1; off < 16; off <<= 1) {
        ps += __shfl_xor(ps, off);
        pd += __shfl_xor(pd, off);
      }
      if ((lane & 15) == 0) {
        int rl = wr * 64 + mi * 16 + (lane >> 4) * 4 + q;
        sred[wc][rl] = ps;
        dred[wc][rl] = pd;
      }
    }
  }
  __syncthreads();
  if (tid < 128) {
    int row = rowBase + tid;
    if (row < M) {
      a_s[row * HEADS + head] = sred[0][tid] + sred[1][tid];
      a_d[row * HEADS + head] = dred[0][tid] + dred[1][tid];
    }
  }
}

// ---------------------------------------------------------------------------
// Single-pass softmax numerators per (node,head): alpha[i*4+h] = exp(leaky(
// a_s[src]+a_d[n])) (no max-shift: logits are O(10), fp32 exp is safe);
// denom[n*4+h] = sum. Aggregate divides once at the end.
__global__ __launch_bounds__(256) void norm_kernel(const int* __restrict__ offsets,
                                                   const int* __restrict__ csr_src,
                                                   const float* __restrict__ a_s,
                                                   const float* __restrict__ a_d,
                                                   float* __restrict__ alpha,
                                                   float* __restrict__ denom, int N) {
  int t = blockIdx.x * 256 + threadIdx.x;
  if (t >= N * HEADS) return;
  int n = t >> 2, hh = t & 3;
  int beg = offsets[n], end = offsets[n + 1];
  float adn = a_d[n * HEADS + hh];
  float den = 0.f;
  for (int i = beg; i < end; i++) {
    float al = a_s[csr_src[i] * HEADS + hh] + adn;
    al = (al > 0.f) ? al : al * NEG_SLOPE;
    float ex = __expf(al);
    alpha[i * HEADS + hh] = ex;
    den += ex;
  }
  denom[t] = den;
}

// ---------------------------------------------------------------------------
// aggregate: block = node, wave = head, 4 edge-slots x 16 lanes; ushort8 rows.
// 2-deep software pipeline per slot group: row load for edge e+8 is issued
// before consuming edge e (doubles loads in flight). Division by softmax
// denominator folded in once at the end.
template <int OUT_BF>
__global__ __launch_bounds__(256) void aggregate_kernel(const unsigned short* __restrict__ h,
                                                        const float* __restrict__ wexp,
                                                        const float* __restrict__ denom,
                                                        const int* __restrict__ offsets,
                                                        const int* __restrict__ csr_src,
                                                        const float* __restrict__ bias,
                                                        void* __restrict__ out, int N) {
  int n = blockIdx.x;
  int w = threadIdx.x >> 6;      // head
  int lane = threadIdx.x & 63;
  int slot = lane >> 4, sl = lane & 15;
  int beg = offsets[n], end = offsets[n + 1];

  float acc[8];
#pragma unroll
  for (int j = 0; j < 8; j++) acc[j] = 0.f;

  // prologue: preload rows for e and e+4 (zero-init keeps masked lanes clean)
  bf16x8 r0 = {}, r1 = {};
  float w0 = 0.f, w1 = 0.f;
  int e = beg + slot;
  if (e < end) {
    int s = csr_src[e];
    w0 = wexp[e * HEADS + w];
    r0 = *(const bf16x8*)&h[(size_t)s * F_OUT + w * HID + sl * 8];
  }
  if (e + 4 < end) {
    int s = csr_src[e + 4];
    w1 = wexp[(e + 4) * HEADS + w];
    r1 = *(const bf16x8*)&h[(size_t)s * F_OUT + w * HID + sl * 8];
  }
  for (; e < end; e += 4) {
    bf16x8 rc = r0; float wc = w0;
    r0 = r1; w0 = w1;
    int en = e + 8;
    if (en < end) {
      int s = csr_src[en];
      w1 = wexp[en * HEADS + w];
      r1 = *(const bf16x8*)&h[(size_t)s * F_OUT + w * HID + sl * 8];
    } else {
      w1 = 0.f;
    }
#pragma unroll
    for (int j = 0; j < 8; j++) acc[j] += bf2f((unsigned short)rc[j]) * wc;
  }
#pragma unroll
  for (int j = 0; j < 8; j++) {
    acc[j] += __shfl_xor(acc[j], 16);
    acc[j] += __shfl_xor(acc[j], 32);
  }

  float inv = 1.f / (denom[n * HEADS + w] + GAT_EPS);
  __shared__ float red[HEADS][HID];
  if (slot == 0) {
#pragma unroll
    for (int j = 0; j < 8; j++) red[w][sl * 8 + j] = acc[j] * inv;
  }
  __syncthreads();
  if (threadIdx.x < HID) {
    int c = threadIdx.x;
    float v = (red[0][c] + red[1][c] + red[2][c] + red[3][c]) * 0.25f + bias[c];
    v = fmaxf(v, 0.f);  // both layers end in relu
    if (OUT_BF)
      ((unsigned short*)out)[(size_t)n * HID + c] = f2b(v);
    else
      ((float*)out)[(size_t)n * HID + c] = v;
  }
}

// ---------------------------------------------------------------------------
extern "C" void kernel_launch(void* const* d_in, const int* in_sizes, int n_in,
                              void* d_out, int out_size, void* d_ws, size_t ws_size,
                              hipStream_t stream) {
  const float* x   = (const float*)d_in[0];
  const int* e32   = (const int*)d_in[1];
  const long long* e64 = (const long long*)d_in[1];
  const float* W1  = (const float*)d_in[2];
  const float* as1 = (const float*)d_in[3];
  const float* ad1 = (const float*)d_in[4];
  const float* b1  = (const float*)d_in[5];
  const float* W2  = (const float*)d_in[6];
  const float* as2 = (const float*)d_in[7];
  const float* ad2 = (const float*)d_in[8];
  const float* b2  = (const float*)d_in[9];

  int F_in = in_sizes[2] / F_OUT;       // 256
  int N = in_sizes[0] / F_in;           // 50000
  int E = in_sizes[1] / 2;              // 400000
  int Etot = E + N;

  char* ws = (char*)d_ws;
  size_t off = 0;
  auto alloc = [&](size_t bytes) -> void* {
    void* p = ws + off;
    off = (off + bytes + 255) & ~(size_t)255;
    return p;
  };
  unsigned short* h_bf   = (unsigned short*)alloc((size_t)N * F_OUT * 2);  // 51.2 MB
  unsigned short* out1_bf= (unsigned short*)alloc((size_t)N * HID * 2);    // 12.8 MB
  unsigned short* Wt1    = (unsigned short*)alloc((size_t)F_in * F_OUT * 2);
  unsigned short* Wt2    = (unsigned short*)alloc((size_t)HID * F_OUT * 2);
  float* a_s    = (float*)alloc((size_t)N * HEADS * 4);
  float* a_d    = (float*)alloc((size_t)N * HEADS * 4);
  float* denom  = (float*)alloc((size_t)N * HEADS * 4);
  float* alpha  = (float*)alloc((size_t)Etot * HEADS * 4);                 // 7.2 MB
  int* counts   = (int*)alloc((size_t)(N + 1) * 4);
  int* offsets  = (int*)alloc((size_t)(N + 1) * 4);
  int* cursor   = (int*)alloc((size_t)N * 4);
  int* csr_src  = (int*)alloc((size_t)Etot * 4);
  int* partials = (int*)alloc(1024 * 4);
  int* flag     = (int*)alloc(256);
  if (off > ws_size) return;

  int nchunks = (N + 1023) / 1024;

  hipMemsetAsync(counts, 0, (size_t)N * 4, stream);
  detect_i64_kernel<<<1, 256, 0, stream>>>((const unsigned int*)d_in[1], flag);
  hist_kernel<<<(Etot + 255) / 256, 256, 0, stream>>>(e32, e64, flag, counts, E, N);
  scan_partial_kernel<<<nchunks, 256, 0, stream>>>(counts, partials, N);
  scan_base_kernel<<<1, 256, 0, stream>>>(partials, offsets, nchunks, N);
  scan_final_kernel<<<nchunks, 256, 0, stream>>>(counts, partials, offsets, cursor, N);
  scatter_kernel<<<(Etot + 255) / 256, 256, 0, stream>>>(e32, e64, flag, cursor, csr_src, E, N);

  cvt_w_kernel<<<(F_in * F_OUT + 255) / 256, 256, 0, stream>>>(W1, Wt1, F_in);
  cvt_w_kernel<<<(HID * F_OUT + 255) / 256, 256, 0, stream>>>(W2, Wt2, HID);

  dim3 ggrid((N + 127) / 128, HEADS);
  int nblocks = (N * HEADS + 255) / 256;
  // ---- layer 1 ----
  gemm_att_kernel<1><<<ggrid, 256, 0, stream>>>(x, Wt1, h_bf, as1, ad1, a_s, a_d, N, F_in);
  norm_kernel<<<nblocks, 256, 0, stream>>>(offsets, csr_src, a_s, a_d, alpha, denom, N);
  aggregate_kernel<1><<<N, 256, 0, stream>>>(h_bf, alpha, denom, offsets, csr_src, b1, out1_bf, N);
  // ---- layer 2 ----
  gemm_att_kernel<0><<<ggrid, 256, 0, stream>>>(out1_bf, Wt2, h_bf, as2, ad2, a_s, a_d, N, HID);
  norm_kernel<<<nblocks, 256, 0, stream>>>(offsets, csr_src, a_s, a_d, alpha, denom, N);
  aggregate_kernel<0><<<N, 256, 0, stream>>>(h_bf, alpha, denom, offsets, csr_src, b2, d_out, N);
}